// Round 17
// baseline (228.688 us; speedup 1.0000x reference)
//
#include <hip/hip_runtime.h>

#define F 64
typedef unsigned int u32;
typedef unsigned long long u64;
typedef short bf16x8 __attribute__((ext_vector_type(8)));
typedef float f32x4 __attribute__((ext_vector_type(4)));

#define SCAN_BLOCK 1024
#define SCAN_ITEMS 4   // elements per thread -> 4096 per block
#define NPART 8        // node partitions
#define EGRP 32        // edge groups per partition (grid = 256)
#define SLICE_MAX 12544
#define SPLITB 512     // split blocks (chunks)
#define SITEMS 8       // edges per thread per split round

// ---- bf16x2 pack/unpack (RNE) ----------------------------------------------
__device__ __forceinline__ u32 pack_bf16x2(float lo, float hi) {
    u32 a = __float_as_uint(lo);
    u32 b = __float_as_uint(hi);
    a = (a + 0x7fffu + ((a >> 16) & 1u)) >> 16;
    b = (b + 0x7fffu + ((b >> 16) & 1u)) >> 16;
    return a | (b << 16);
}
__device__ __forceinline__ float unpack_lo(u32 p) { return __uint_as_float(p << 16); }
__device__ __forceinline__ float unpack_hi(u32 p) { return __uint_as_float(p & 0xffff0000u); }

// ---------------------------------------------------------------------------
// k_prepw: one block. W (f32, 32KB) -> Btp[128][64] bf16, kgroup-swizzled
// (kg ^= f2&7). Done once; k_gemm blocks then copy it coalesced into LDS.
// ---------------------------------------------------------------------------
__global__ __launch_bounds__(256) void k_prepw(
    const float* __restrict__ weight, unsigned short* __restrict__ Btp)
{
    const int t = threadIdx.x;
    for (int i = t; i < 128 * 64; i += 256) {
        const int f2 = i >> 6;
        const int k  = i & 63;
        const float wv = weight[(f2 >= 64 ? F * F : 0) + k * F + (f2 & 63)];
        Btp[f2 * 64 + (((k >> 3) ^ (f2 & 7)) << 3) + (k & 7)] =
            (unsigned short)(pack_bf16x2(wv, 0.f) & 0xffffu);
    }
}

// ---------------------------------------------------------------------------
// k_gemm (MFMA): [128 rows (node-interleaved real/imag) x 64k] @ [64k x 128f].
//   initp[n][f] = pack_bf16(x_r@W0+b, x_i@W0+b)   (f < 64)
//   x1p[n][f]   = pack_bf16(x_r@W1,   x_i@W1)     (f >= 64)
// Bt copied coalesced from pre-swizzled Btp.
// ---------------------------------------------------------------------------
__global__ __launch_bounds__(256, 4) void k_gemm(
    const float* __restrict__ x_real, const float* __restrict__ x_imag,
    const unsigned short* __restrict__ Btp, const float* __restrict__ bias,
    u32* __restrict__ x1p, u32* __restrict__ initp, int n_nodes)
{
    __shared__ unsigned short lds[2 * 128 * 64];   // 32 KB
    unsigned short* __restrict__ A  = lds;
    unsigned short* __restrict__ Bt = lds + 128 * 64;

    const int t = threadIdx.x;
    const int base = blockIdx.x * 64;   // node base

    // ---- stage A: x rows, row = 2*ln + (0 real | 1 imag), bf16, swizzled ----
#pragma unroll
    for (int c = 0; c < 8; ++c) {
        const int fq  = t + 256 * c;          // 2048 float4 slots
        const int arr = fq >> 10;
        const int rem = fq & 1023;
        const int ln  = rem >> 4;
        const int c4  = rem & 15;
        const int g   = base + ln;
        const float* __restrict__ s = arr ? x_imag : x_real;
        float4 v = make_float4(0.f, 0.f, 0.f, 0.f);
        if (g < n_nodes) v = *(const float4*)(s + (size_t)g * F + c4 * 4);
        const int row  = 2 * ln + arr;
        const int kg   = c4 >> 1;
        const int half = c4 & 1;
        u32* dst = (u32*)&A[row * 64 + ((kg ^ (row & 7)) << 3) + (half << 2)];
        dst[0] = pack_bf16x2(v.x, v.y);
        dst[1] = pack_bf16x2(v.z, v.w);
    }

    // ---- stage Bt: coalesced 16 KB copy of pre-swizzled Btp ----
#pragma unroll
    for (int i = 0; i < 4; ++i) {
        const int idx = t + 256 * i;           // 1024 uint4 slots
        ((uint4*)Bt)[idx] = ((const uint4*)Btp)[idx];
    }
    __syncthreads();

    // ---- MFMA compute: wave w -> rows [w*32, w*32+32), all 128 cols ----
    const int l   = t & 63;
    const int w   = t >> 6;
    const int l15 = l & 15;
    const int lg  = l >> 4;

    f32x4 acc[2][8];
#pragma unroll
    for (int tr = 0; tr < 2; ++tr)
#pragma unroll
        for (int tc = 0; tc < 8; ++tc)
            acc[tr][tc] = (f32x4){0.f, 0.f, 0.f, 0.f};

#pragma unroll
    for (int ks = 0; ks < 2; ++ks) {
        bf16x8 af[2];
#pragma unroll
        for (int tr = 0; tr < 2; ++tr) {
            const int row = w * 32 + tr * 16 + l15;
            const int kg  = ks * 4 + lg;
            af[tr] = *(const bf16x8*)&A[row * 64 + ((kg ^ (row & 7)) << 3)];
        }
#pragma unroll
        for (int tc = 0; tc < 8; ++tc) {
            const int f2 = tc * 16 + l15;
            const int kg = ks * 4 + lg;
            const bf16x8 bfr = *(const bf16x8*)&Bt[f2 * 64 + ((kg ^ (f2 & 7)) << 3)];
#pragma unroll
            for (int tr = 0; tr < 2; ++tr)
                acc[tr][tc] = __builtin_amdgcn_mfma_f32_16x16x32_bf16(
                    af[tr], bfr, acc[tr][tc], 0, 0, 0);
        }
    }

    // ---- epilogue: acc regs {0,1} = (real,imag) node g0; {2,3} = node g0+1 ----
#pragma unroll
    for (int tc = 0; tc < 8; ++tc) {
        const int f2 = tc * 16 + l15;
        const float bv = (f2 < F) ? bias[f2] : 0.f;
#pragma unroll
        for (int tr = 0; tr < 2; ++tr) {
            const int row0 = w * 32 + tr * 16 + lg * 4;
            const int g0 = base + (row0 >> 1);
            const int g1 = g0 + 1;
            const f32x4 a = acc[tr][tc];
            if (f2 < F) {
                if (g0 < n_nodes) initp[(size_t)g0 * F + f2] = pack_bf16x2(a[0] + bv, a[1] + bv);
                if (g1 < n_nodes) initp[(size_t)g1 * F + f2] = pack_bf16x2(a[2] + bv, a[3] + bv);
            } else {
                const int f = f2 - F;
                if (g0 < n_nodes) x1p[(size_t)g0 * F + f] = pack_bf16x2(a[0], a[1]);
                if (g1 < n_nodes) x1p[(size_t)g1 * F + f] = pack_bf16x2(a[2], a[3]);
            }
        }
    }
}

// ---------------------------------------------------------------------------
// k_coarse: per-(block, partition) counts, plain stores. ZERO global atomics.
// ---------------------------------------------------------------------------
__global__ __launch_bounds__(256) void k_coarse(
    const int* __restrict__ src, int* __restrict__ bcnt,
    int n_edges, int slice, int chunk)
{
    __shared__ int c[NPART];
    const int t = threadIdx.x;
    if (t < NPART) c[t] = 0;
    __syncthreads();
    const int cbeg = blockIdx.x * chunk;
    const int cend = min(cbeg + chunk, n_edges);
    for (int e = cbeg + t; e < cend; e += 256)
        atomicAdd(&c[(u32)src[e] / (u32)slice], 1);
    __syncthreads();
    if (t < NPART) bcnt[blockIdx.x * NPART + t] = c[t];
}

// ---------------------------------------------------------------------------
// k_base2: one block. Partition-major scan of bcnt -> bbase + pbase[9].
// ---------------------------------------------------------------------------
__global__ __launch_bounds__(SPLITB) void k_base2(
    const int* __restrict__ bcnt, int* __restrict__ bbase, int* __restrict__ pbase)
{
    __shared__ int wsum[SPLITB / 64];
    __shared__ int total[NPART];
    __shared__ int pb[NPART + 1];
    const int t = threadIdx.x;
    const int lane = t & 63, wid = t >> 6;

    for (int p = 0; p < NPART; ++p) {
        const int v = bcnt[t * NPART + p];
        int incl = v;
#pragma unroll
        for (int d = 1; d < 64; d <<= 1) {
            int x = __shfl_up(incl, d);
            if (lane >= d) incl += x;
        }
        if (lane == 63) wsum[wid] = incl;
        __syncthreads();
        if (wid == 0) {
            int s = (lane < SPLITB / 64) ? wsum[lane] : 0;
#pragma unroll
            for (int d = 1; d < SPLITB / 64; d <<= 1) {
                int x = __shfl_up(s, d);
                if (lane >= d) s += x;
            }
            if (lane < SPLITB / 64) wsum[lane] = s;
        }
        __syncthreads();
        const int excl = (incl - v) + (wid ? wsum[wid - 1] : 0);
        bbase[t * NPART + p] = excl;
        if (t == SPLITB - 1) total[p] = excl + v;
        __syncthreads();
    }
    if (t == 0) {
        int run = 0;
        for (int p = 0; p < NPART; ++p) { pb[p] = run; run += total[p]; }
        pb[NPART] = run;
        for (int p = 0; p <= NPART; ++p) pbase[p] = pb[p];
    }
    __syncthreads();
    for (int p = 0; p < NPART; ++p)
        bbase[t * NPART + p] += pb[p];
}

// ---------------------------------------------------------------------------
// k_split: ONE pass, ZERO global atomics. LDS cursors seeded from bbase;
// 2048 edges per round (SITEMS=8).
// ---------------------------------------------------------------------------
__global__ __launch_bounds__(256) void k_split(
    const int* __restrict__ ei, const float* __restrict__ nr, const float* __restrict__ ni,
    const int* __restrict__ bbase, u32* __restrict__ ssrc, u64* __restrict__ smrec,
    int n_edges, int slice, int chunk)
{
    __shared__ int cnt[NPART];
    __shared__ int gb[NPART];
    __shared__ int lcur[NPART];
    const int t = threadIdx.x;
    if (t < NPART) lcur[t] = bbase[blockIdx.x * NPART + t];
    const int cbeg = blockIdx.x * chunk;
    const int cend = min(cbeg + chunk, n_edges);

    for (int base = cbeg; base < cend; base += 256 * SITEMS) {
        if (t < NPART) cnt[t] = 0;
        __syncthreads();
        int p[SITEMS], lpos[SITEMS];
        u32 s[SITEMS]; u64 mrec[SITEMS];
#pragma unroll
        for (int j = 0; j < SITEMS; ++j) {
            const int e = base + t + 256 * j;
            if (e < cend) {
                s[j] = (u32)ei[e];
                const u32 d = (u32)ei[n_edges + e];
                const u32 nn = pack_bf16x2(nr[e], ni[e]);
                mrec[j] = (u64)d | ((u64)nn << 32);
                p[j] = (int)(s[j] / (u32)slice);
                lpos[j] = atomicAdd(&cnt[p[j]], 1);
            } else p[j] = -1;
        }
        __syncthreads();
        if (t < NPART) { gb[t] = lcur[t]; lcur[t] += cnt[t]; }
        __syncthreads();
#pragma unroll
        for (int j = 0; j < SITEMS; ++j) {
            if (p[j] >= 0) {
                const int gi = gb[p[j]] + lpos[j];
                ssrc[gi]  = s[j];
                smrec[gi] = mrec[j];
            }
        }
        __syncthreads();
    }
}

// ---------------------------------------------------------------------------
// k_hist8: per (part, grp): LDS histogram of staged src -> priv[grp][node].
// ---------------------------------------------------------------------------
__global__ __launch_bounds__(1024) void k_hist8(
    const u32* __restrict__ ssrc, const int* __restrict__ pbase,
    int* __restrict__ priv, int n_nodes, int slice)
{
    __shared__ int h[SLICE_MAX];
    const int p = blockIdx.x & (NPART - 1);
    const int g = blockIdx.x >> 3;
    const int t = threadIdx.x;

    const int lo = p * slice;
    const int hi = min(lo + slice, n_nodes);
    const int sl = hi - lo;
    if (sl <= 0) return;

    for (int i = t; i < sl; i += 1024) h[i] = 0;
    __syncthreads();

    const int pb = pbase[p], pe = pbase[p + 1];
    const long long len = pe - pb;
    const int beg = pb + (int)(len * g / EGRP);
    const int end = pb + (int)(len * (g + 1) / EGRP);
    for (int e = beg + t; e < end; e += 1024)
        atomicAdd(&h[(int)ssrc[e] - lo], 1);
    __syncthreads();

    int* __restrict__ dst = priv + (size_t)g * n_nodes + lo;
    for (int i = t; i < sl; i += 1024) dst[i] = h[i];
}

// ---------------------------------------------------------------------------
// Scan pass 1.
// ---------------------------------------------------------------------------
__global__ __launch_bounds__(1024) void k_scan1(
    const int* __restrict__ priv, int* __restrict__ pre,
    int* __restrict__ partials, int n, int n_nodes)
{
    __shared__ int wsum[16];
    const int t = threadIdx.x;
    const int lane = t & 63, wid = t >> 6;
    const int base = blockIdx.x * (SCAN_BLOCK * SCAN_ITEMS) + t * SCAN_ITEMS;

    int v[SCAN_ITEMS];
    int local = 0;
#pragma unroll
    for (int j = 0; j < SCAN_ITEMS; ++j) {
        const int idx = base + j;
        int c = 0;
        if (idx < n) {
            for (int g = 0; g < EGRP; ++g) c += priv[(size_t)g * n_nodes + idx];
        }
        v[j] = local;
        local += c;
    }
    int incl = local;
#pragma unroll
    for (int d = 1; d < 64; d <<= 1) {
        int x = __shfl_up(incl, d);
        if (lane >= d) incl += x;
    }
    if (lane == 63) wsum[wid] = incl;
    __syncthreads();
    if (wid == 0) {
        int s = (lane < 16) ? wsum[lane] : 0;
#pragma unroll
        for (int d = 1; d < 16; d <<= 1) {
            int x = __shfl_up(s, d);
            if (lane >= d) s += x;
        }
        if (lane < 16) wsum[lane] = s;
    }
    __syncthreads();
    const int texcl = (incl - local) + (wid ? wsum[wid - 1] : 0);
#pragma unroll
    for (int j = 0; j < SCAN_ITEMS; ++j) {
        const int idx = base + j;
        if (idx < n) pre[idx] = texcl + v[j];
    }
    if (t == SCAN_BLOCK - 1) partials[blockIdx.x] = texcl + local;
}

// Pass 2: final offsets + per-grp sub-offsets IN-PLACE over priv.
__global__ __launch_bounds__(1024) void k_scan2(
    int* __restrict__ pre, const int* __restrict__ partials,
    int* __restrict__ po, int n, int n_nodes, int n_edges)
{
    __shared__ int s_off;
    const int t = threadIdx.x;
    if (t < 64) {
        int val = (t < blockIdx.x) ? partials[t] : 0;
#pragma unroll
        for (int d = 32; d > 0; d >>= 1) val += __shfl_down(val, d);
        if (t == 0) s_off = val;
    }
    __syncthreads();
    const int boff = s_off;
    const int base = blockIdx.x * (SCAN_BLOCK * SCAN_ITEMS) + t * SCAN_ITEMS;
#pragma unroll
    for (int j = 0; j < SCAN_ITEMS; ++j) {
        const int idx = base + j;
        if (idx < n) {
            const int o = boff + pre[idx];
            pre[idx] = o;
            int running = o;
            for (int g = 0; g < EGRP; ++g) {
                const size_t ix = (size_t)g * n_nodes + idx;
                const int c = po[ix];
                po[ix] = running;
                running += c;
            }
        }
    }
    if (blockIdx.x == 0 && t == 0) pre[n] = n_edges;
}

// ---------------------------------------------------------------------------
// k_place3: LDS cursors seeded from off2; partition-local staged reads.
// ---------------------------------------------------------------------------
__global__ __launch_bounds__(1024) void k_place3(
    const u32* __restrict__ ssrc, const u64* __restrict__ smrec,
    const int* __restrict__ pbase, const int* __restrict__ off2,
    u64* __restrict__ meta2, int n_nodes, int slice)
{
    __shared__ int cur[SLICE_MAX];
    const int p = blockIdx.x & (NPART - 1);
    const int g = blockIdx.x >> 3;
    const int t = threadIdx.x;

    const int lo = p * slice;
    const int hi = min(lo + slice, n_nodes);
    const int sl = hi - lo;
    if (sl <= 0) return;

    const int* __restrict__ o2 = off2 + (size_t)g * n_nodes + lo;
    for (int i = t; i < sl; i += 1024) cur[i] = o2[i];
    __syncthreads();

    const int pb = pbase[p], pe = pbase[p + 1];
    const long long len = pe - pb;
    const int beg = pb + (int)(len * g / EGRP);
    const int end = pb + (int)(len * (g + 1) / EGRP);
    for (int e = beg + t; e < end; e += 1024) {
        const int s = (int)ssrc[e];
        const int pos = atomicAdd(&cur[s - lo], 1);
        meta2[pos] = smrec[e];
    }
}

// ---------------------------------------------------------------------------
// Gather: partitioned; nt loads for one-touch streams (meta2, initp).
// ---------------------------------------------------------------------------
#define APPLY2(m, p, aR, aI)                                  \
    do {                                                      \
        const u32 nnv = (u32)((m) >> 32);                     \
        const float cr = unpack_lo(nnv);                      \
        const float ci = unpack_hi(nnv);                      \
        const float xr = unpack_lo(p);                        \
        const float xi = unpack_hi(p);                        \
        aR = fmaf(cr, xr, fmaf(-ci, xi, aR));                 \
        aI = fmaf(cr, xi, fmaf(ci, xr, aI));                  \
    } while (0)

__global__ __launch_bounds__(256) void k_gather(
    const u32* __restrict__ x1p, const u32* __restrict__ initp,
    const int* __restrict__ offsets, const u64* __restrict__ meta2,
    float* __restrict__ out_real, float* __restrict__ out_imag,
    int n_nodes, int slice)
{
    const int part = blockIdx.x & (NPART - 1);
    const int lane = threadIdx.x & 63;
    const int wip = ((blockIdx.x >> 3) << 2) + (threadIdx.x >> 6);
    const int wpp = (gridDim.x >> 3) << 2;

    const int lo = part * slice;
    const int hi = min(lo + slice, n_nodes);
    if (hi <= lo) return;
    const int chunk = (hi - lo + wpp - 1) / wpp;
    const int nbeg = lo + wip * chunk;
    const int nend = min(nbeg + chunk, hi);

    for (int n = nbeg; n < nend; ++n) {
        const int nu = __builtin_amdgcn_readfirstlane(n);
        const int beg = __builtin_amdgcn_readfirstlane(offsets[nu]);
        const int end = __builtin_amdgcn_readfirstlane(offsets[nu + 1]);

        float aR0 = 0.f, aI0 = 0.f, aR1 = 0.f, aI1 = 0.f;
        float aR2 = 0.f, aI2 = 0.f, aR3 = 0.f, aI3 = 0.f;

        int e = beg;
        for (; e + 8 <= end; e += 8) {
            const u64 m0 = __builtin_nontemporal_load(meta2 + e + 0);
            const u64 m1 = __builtin_nontemporal_load(meta2 + e + 1);
            const u64 m2 = __builtin_nontemporal_load(meta2 + e + 2);
            const u64 m3 = __builtin_nontemporal_load(meta2 + e + 3);
            const u64 m4 = __builtin_nontemporal_load(meta2 + e + 4);
            const u64 m5 = __builtin_nontemporal_load(meta2 + e + 5);
            const u64 m6 = __builtin_nontemporal_load(meta2 + e + 6);
            const u64 m7 = __builtin_nontemporal_load(meta2 + e + 7);
            const u32 p0 = x1p[(size_t)(u32)m0 * F + lane];
            const u32 p1 = x1p[(size_t)(u32)m1 * F + lane];
            const u32 p2 = x1p[(size_t)(u32)m2 * F + lane];
            const u32 p3 = x1p[(size_t)(u32)m3 * F + lane];
            const u32 p4 = x1p[(size_t)(u32)m4 * F + lane];
            const u32 p5 = x1p[(size_t)(u32)m5 * F + lane];
            const u32 p6 = x1p[(size_t)(u32)m6 * F + lane];
            const u32 p7 = x1p[(size_t)(u32)m7 * F + lane];
            APPLY2(m0, p0, aR0, aI0);
            APPLY2(m1, p1, aR1, aI1);
            APPLY2(m2, p2, aR2, aI2);
            APPLY2(m3, p3, aR3, aI3);
            APPLY2(m4, p4, aR0, aI0);
            APPLY2(m5, p5, aR1, aI1);
            APPLY2(m6, p6, aR2, aI2);
            APPLY2(m7, p7, aR3, aI3);
        }
        for (; e + 4 <= end; e += 4) {
            const u64 m0 = __builtin_nontemporal_load(meta2 + e + 0);
            const u64 m1 = __builtin_nontemporal_load(meta2 + e + 1);
            const u64 m2 = __builtin_nontemporal_load(meta2 + e + 2);
            const u64 m3 = __builtin_nontemporal_load(meta2 + e + 3);
            const u32 p0 = x1p[(size_t)(u32)m0 * F + lane];
            const u32 p1 = x1p[(size_t)(u32)m1 * F + lane];
            const u32 p2 = x1p[(size_t)(u32)m2 * F + lane];
            const u32 p3 = x1p[(size_t)(u32)m3 * F + lane];
            APPLY2(m0, p0, aR0, aI0);
            APPLY2(m1, p1, aR1, aI1);
            APPLY2(m2, p2, aR2, aI2);
            APPLY2(m3, p3, aR3, aI3);
        }
        for (; e < end; ++e) {
            const u64 m = __builtin_nontemporal_load(meta2 + e);
            const u32 p = x1p[(size_t)(u32)m * F + lane];
            APPLY2(m, p, aR0, aI0);
        }

        const size_t b = (size_t)nu * F + lane;
        const u32 iw = __builtin_nontemporal_load(initp + b); // aliases out_real[b]
        const float oR = unpack_lo(iw) + ((aR0 + aR1) + (aR2 + aR3));
        const float oI = unpack_hi(iw) + ((aI0 + aI1) + (aI2 + aI3));
        __builtin_nontemporal_store(oR, &out_real[b]);
        __builtin_nontemporal_store(oI, &out_imag[b]);
    }
}

// ---------------------------------------------------------------------------
// Fallback (ws too small or slice too big): f32 init + atomic scatter.
// ---------------------------------------------------------------------------
__global__ __launch_bounds__(256) void k_init_out(
    const float* __restrict__ x_real, const float* __restrict__ x_imag,
    const float* __restrict__ weight, const float* __restrict__ bias,
    float* __restrict__ out_real, float* __restrict__ out_imag, int n_nodes)
{
    const int lane = threadIdx.x & 63;
    const int waveId = (blockIdx.x * blockDim.x + threadIdx.x) >> 6;
    const int nWaves = (gridDim.x * blockDim.x) >> 6;
    const float* __restrict__ W0 = weight;
    float w0c[F];
#pragma unroll
    for (int k = 0; k < F; ++k) w0c[k] = W0[k * F + lane];
    const float bf = bias[lane];
    for (int n = waveId; n < n_nodes; n += nWaves) {
        const int nu = __builtin_amdgcn_readfirstlane(n);
        const float4* __restrict__ xr4 = (const float4*)(x_real + (size_t)nu * F);
        const float4* __restrict__ xi4 = (const float4*)(x_imag + (size_t)nu * F);
        float gR = 0.f, gI = 0.f;
#pragma unroll
        for (int k4 = 0; k4 < F / 4; ++k4) {
            const float4 vr = xr4[k4];
            const float4 vi = xi4[k4];
            const float xr[4] = {vr.x, vr.y, vr.z, vr.w};
            const float xi[4] = {vi.x, vi.y, vi.z, vi.w};
#pragma unroll
            for (int j = 0; j < 4; ++j) {
                const int k = 4 * k4 + j;
                gR = fmaf(xr[j], w0c[k], gR);
                gI = fmaf(xi[j], w0c[k], gI);
            }
        }
        const size_t b = (size_t)nu * F + lane;
        out_real[b] = gR + bf;
        out_imag[b] = gI + bf;
    }
}

__global__ __launch_bounds__(256) void k_x1_only(
    const float* __restrict__ x_real, const float* __restrict__ x_imag,
    const float* __restrict__ weight, u32* __restrict__ x1p, int n_nodes)
{
    const int lane = threadIdx.x & 63;
    const int waveId = (blockIdx.x * blockDim.x + threadIdx.x) >> 6;
    const int nWaves = (gridDim.x * blockDim.x) >> 6;
    const float* __restrict__ W1 = weight + F * F;
    float w1c[F];
#pragma unroll
    for (int k = 0; k < F; ++k) w1c[k] = W1[k * F + lane];
    for (int n = waveId; n < n_nodes; n += nWaves) {
        const int nu = __builtin_amdgcn_readfirstlane(n);
        const float4* __restrict__ xr4 = (const float4*)(x_real + (size_t)nu * F);
        const float4* __restrict__ xi4 = (const float4*)(x_imag + (size_t)nu * F);
        float aR = 0.f, aI = 0.f;
#pragma unroll
        for (int k4 = 0; k4 < F / 4; ++k4) {
            const float4 vr = xr4[k4];
            const float4 vi = xi4[k4];
            const float xr[4] = {vr.x, vr.y, vr.z, vr.w};
            const float xi[4] = {vi.x, vi.y, vi.z, vi.w};
#pragma unroll
            for (int j = 0; j < 4; ++j) {
                const int k = 4 * k4 + j;
                aR = fmaf(xr[j], w1c[k], aR);
                aI = fmaf(xi[j], w1c[k], aI);
            }
        }
        x1p[(size_t)nu * F + lane] = pack_bf16x2(aR, aI);
    }
}

__global__ __launch_bounds__(256) void k_scatter(
    const u32* __restrict__ x1p, const int* __restrict__ edge_index,
    const float* __restrict__ norm_real, const float* __restrict__ norm_imag,
    float* __restrict__ out_real, float* __restrict__ out_imag, int n_edges)
{
    const long long gid = (long long)blockIdx.x * blockDim.x + threadIdx.x;
    const long long total = (long long)n_edges * 16;
    if (gid >= total) return;
    const int e = (int)(gid >> 4);
    const int c = (int)(gid & 15);
    const int s = edge_index[e];
    const int d = edge_index[n_edges + e];
    const float cr = norm_real[e];
    const float ci = norm_imag[e];
    const uint4 p4 = *(const uint4*)(x1p + (size_t)d * F + c * 4);
    const u32 pp[4] = {p4.x, p4.y, p4.z, p4.w};
    float* __restrict__ pr = out_real + (size_t)s * F + c * 4;
    float* __restrict__ pi = out_imag + (size_t)s * F + c * 4;
#pragma unroll
    for (int j = 0; j < 4; ++j) {
        const float xr = unpack_lo(pp[j]);
        const float xi = unpack_hi(pp[j]);
        unsafeAtomicAdd(pr + j, fmaf(cr, xr, -ci * xi));
        unsafeAtomicAdd(pi + j, fmaf(cr, xi, ci * xr));
    }
}

extern "C" void kernel_launch(void* const* d_in, const int* in_sizes, int n_in,
                              void* d_out, int out_size, void* d_ws, size_t ws_size,
                              hipStream_t stream) {
    const float* x_real     = (const float*)d_in[0];
    const float* x_imag     = (const float*)d_in[1];
    const float* weight     = (const float*)d_in[2];
    const float* bias       = (const float*)d_in[3];
    const float* norm_real  = (const float*)d_in[4];
    const float* norm_imag  = (const float*)d_in[5];
    const int*   edge_index = (const int*)d_in[6];

    const int n_nodes = in_sizes[0] / F;
    const int n_edges = in_sizes[4];
    const int slice   = (n_nodes + NPART - 1) / NPART;

    float* out_real = (float*)d_out;
    float* out_imag = out_real + (size_t)n_nodes * F;
    u32*   initp    = (u32*)d_out;   // packed bf16 init, overwritten by gather

    // ws layout:
    //   region A: staged ssrc(E*4)+smrec(E*8) during CSR build, then x1p
    //   [meta2][offsets][priv(=off2)][partials][bcnt][bbase][pbase][Btp]
    char* ws = (char*)d_ws;
    const size_t x1_bytes     = (size_t)n_nodes * F * sizeof(u32);
    const size_t staged_bytes = (size_t)n_edges * 12;
    const size_t A_bytes      = (x1_bytes > staged_bytes ? x1_bytes : staged_bytes + 8);
    const size_t meta_bytes   = (size_t)n_edges * sizeof(u64);
    const size_t off_bytes    = (size_t)(n_nodes + 1) * sizeof(int);
    const size_t priv_bytes   = (size_t)EGRP * n_nodes * sizeof(int);
    const size_t par_bytes    = 64 * sizeof(int);
    const size_t bcnt_bytes   = (size_t)SPLITB * NPART * sizeof(int);
    const size_t bbase_bytes  = (size_t)SPLITB * NPART * sizeof(int);
    const size_t pbase_bytes  = 64 * sizeof(int);
    const size_t btp_bytes    = 128 * 64 * sizeof(unsigned short);   // 16 KB
    const size_t need = A_bytes + meta_bytes + off_bytes + priv_bytes + par_bytes
                      + bcnt_bytes + bbase_bytes + pbase_bytes + btp_bytes;

    u32* x1p      = (u32*)ws;
    u32* ssrc     = (u32*)ws;
    u64* smrec    = (u64*)(ws + (size_t)n_edges * sizeof(u32));
    u64* meta2    = (u64*)(ws + A_bytes);
    int* offsets  = (int*)(ws + A_bytes + meta_bytes);
    int* priv     = (int*)(ws + A_bytes + meta_bytes + off_bytes);
    int* partials = (int*)(ws + A_bytes + meta_bytes + off_bytes + priv_bytes);
    int* bcnt     = partials + 64;
    int* bbase    = bcnt + SPLITB * NPART;
    int* pbase    = bbase + SPLITB * NPART;
    unsigned short* Btp = (unsigned short*)(pbase + 64);

    if (ws_size >= need && slice <= SLICE_MAX) {
        const int schunk = (n_edges + SPLITB - 1) / SPLITB;
        // --- weight prep (tiny, once) ---
        k_prepw<<<1, 256, 0, stream>>>(weight, Btp);
        // --- CSR build: deterministic single-pass split, zero global atomics ---
        k_coarse<<<SPLITB, 256, 0, stream>>>(edge_index, bcnt, n_edges, slice, schunk);
        k_base2<<<1, SPLITB, 0, stream>>>(bcnt, bbase, pbase);
        k_split<<<SPLITB, 256, 0, stream>>>(edge_index, norm_real, norm_imag,
                                            bbase, ssrc, smrec, n_edges, slice, schunk);
        k_hist8<<<NPART * EGRP, 1024, 0, stream>>>(ssrc, pbase, priv, n_nodes, slice);
        const int sblocks = (n_nodes + SCAN_BLOCK * SCAN_ITEMS - 1) / (SCAN_BLOCK * SCAN_ITEMS);
        k_scan1<<<sblocks, SCAN_BLOCK, 0, stream>>>(priv, offsets, partials, n_nodes, n_nodes);
        k_scan2<<<sblocks, SCAN_BLOCK, 0, stream>>>(offsets, partials, priv,
                                                    n_nodes, n_nodes, n_edges);
        k_place3<<<NPART * EGRP, 1024, 0, stream>>>(ssrc, smrec, pbase, priv,
                                                    meta2, n_nodes, slice);
        // --- dense init via MFMA (x1p overwrites staging) + gather ---
        const int gblocks = (n_nodes + 63) / 64;
        k_gemm<<<gblocks, 256, 0, stream>>>(
            x_real, x_imag, Btp, bias, x1p, initp, n_nodes);
        k_gather<<<2048, 256, 0, stream>>>(
            x1p, initp, offsets, meta2, out_real, out_imag, n_nodes, slice);
    } else {
        k_init_out<<<2048, 256, 0, stream>>>(
            x_real, x_imag, weight, bias, out_real, out_imag, n_nodes);
        k_x1_only<<<2048, 256, 0, stream>>>(x_real, x_imag, weight, x1p, n_nodes);
        const long long work = (long long)n_edges * 16;
        const int blocks = (int)((work + 255) / 256);
        k_scatter<<<blocks, 256, 0, stream>>>(
            x1p, edge_index, norm_real, norm_imag, out_real, out_imag, n_edges);
    }
}

// Round 18
// 208.297 us; speedup vs baseline: 1.0979x; 1.0979x over previous
//
#include <hip/hip_runtime.h>

#define F 64
typedef unsigned int u32;
typedef unsigned long long u64;
typedef short bf16x8 __attribute__((ext_vector_type(8)));
typedef float f32x4 __attribute__((ext_vector_type(4)));

#define SCAN_BLOCK 1024
#define SCAN_ITEMS 4   // elements per thread -> 4096 per block
#define NPART 8        // node partitions
#define EGRP 16        // edge groups per partition (grid = 128)
#define SLICE_MAX 12544
#define SPLITB 512     // split blocks (chunks)
#define SITEMS 8       // edges per thread per split round

// ---- bf16x2 pack/unpack (RNE) ----------------------------------------------
__device__ __forceinline__ u32 pack_bf16x2(float lo, float hi) {
    u32 a = __float_as_uint(lo);
    u32 b = __float_as_uint(hi);
    a = (a + 0x7fffu + ((a >> 16) & 1u)) >> 16;
    b = (b + 0x7fffu + ((b >> 16) & 1u)) >> 16;
    return a | (b << 16);
}
__device__ __forceinline__ float unpack_lo(u32 p) { return __uint_as_float(p << 16); }
__device__ __forceinline__ float unpack_hi(u32 p) { return __uint_as_float(p & 0xffff0000u); }

// ---------------------------------------------------------------------------
// k_coarse: per-(block, partition) counts (blocks 0..SPLITB-1) + weight prep
// (block SPLITB): W f32 -> Btp[128][64] bf16 kgroup-swizzled.
// ---------------------------------------------------------------------------
__global__ __launch_bounds__(256) void k_coarse(
    const int* __restrict__ src, int* __restrict__ bcnt,
    const float* __restrict__ weight, unsigned short* __restrict__ Btp,
    int n_edges, int slice, int chunk)
{
    const int t = threadIdx.x;
    if (blockIdx.x == SPLITB) {
        for (int i = t; i < 128 * 64; i += 256) {
            const int f2 = i >> 6;
            const int k  = i & 63;
            const float wv = weight[(f2 >= 64 ? F * F : 0) + k * F + (f2 & 63)];
            Btp[f2 * 64 + (((k >> 3) ^ (f2 & 7)) << 3) + (k & 7)] =
                (unsigned short)(pack_bf16x2(wv, 0.f) & 0xffffu);
        }
        return;
    }
    __shared__ int c[NPART];
    if (t < NPART) c[t] = 0;
    __syncthreads();
    const int cbeg = blockIdx.x * chunk;
    const int cend = min(cbeg + chunk, n_edges);
    for (int e = cbeg + t; e < cend; e += 256)
        atomicAdd(&c[(u32)src[e] / (u32)slice], 1);
    __syncthreads();
    if (t < NPART) bcnt[blockIdx.x * NPART + t] = c[t];
}

// ---------------------------------------------------------------------------
// k_base2: one block. Partition-major scan of bcnt -> bbase + pbase[9].
// ---------------------------------------------------------------------------
__global__ __launch_bounds__(SPLITB) void k_base2(
    const int* __restrict__ bcnt, int* __restrict__ bbase, int* __restrict__ pbase)
{
    __shared__ int wsum[SPLITB / 64];
    __shared__ int total[NPART];
    __shared__ int pb[NPART + 1];
    const int t = threadIdx.x;
    const int lane = t & 63, wid = t >> 6;

    for (int p = 0; p < NPART; ++p) {
        const int v = bcnt[t * NPART + p];
        int incl = v;
#pragma unroll
        for (int d = 1; d < 64; d <<= 1) {
            int x = __shfl_up(incl, d);
            if (lane >= d) incl += x;
        }
        if (lane == 63) wsum[wid] = incl;
        __syncthreads();
        if (wid == 0) {
            int s = (lane < SPLITB / 64) ? wsum[lane] : 0;
#pragma unroll
            for (int d = 1; d < SPLITB / 64; d <<= 1) {
                int x = __shfl_up(s, d);
                if (lane >= d) s += x;
            }
            if (lane < SPLITB / 64) wsum[lane] = s;
        }
        __syncthreads();
        const int excl = (incl - v) + (wid ? wsum[wid - 1] : 0);
        bbase[t * NPART + p] = excl;
        if (t == SPLITB - 1) total[p] = excl + v;
        __syncthreads();
    }
    if (t == 0) {
        int run = 0;
        for (int p = 0; p < NPART; ++p) { pb[p] = run; run += total[p]; }
        pb[NPART] = run;
        for (int p = 0; p <= NPART; ++p) pbase[p] = pb[p];
    }
    __syncthreads();
    for (int p = 0; p < NPART; ++p)
        bbase[t * NPART + p] += pb[p];
}

// ---------------------------------------------------------------------------
// k_split: ONE pass, ZERO global atomics. LDS cursors seeded from bbase.
// ---------------------------------------------------------------------------
__global__ __launch_bounds__(256) void k_split(
    const int* __restrict__ ei, const float* __restrict__ nr, const float* __restrict__ ni,
    const int* __restrict__ bbase, u32* __restrict__ ssrc, u64* __restrict__ smrec,
    int n_edges, int slice, int chunk)
{
    __shared__ int cnt[NPART];
    __shared__ int gb[NPART];
    __shared__ int lcur[NPART];
    const int t = threadIdx.x;
    if (t < NPART) lcur[t] = bbase[blockIdx.x * NPART + t];
    const int cbeg = blockIdx.x * chunk;
    const int cend = min(cbeg + chunk, n_edges);

    for (int base = cbeg; base < cend; base += 256 * SITEMS) {
        if (t < NPART) cnt[t] = 0;
        __syncthreads();
        int p[SITEMS], lpos[SITEMS];
        u32 s[SITEMS]; u64 mrec[SITEMS];
#pragma unroll
        for (int j = 0; j < SITEMS; ++j) {
            const int e = base + t + 256 * j;
            if (e < cend) {
                s[j] = (u32)ei[e];
                const u32 d = (u32)ei[n_edges + e];
                const u32 nn = pack_bf16x2(nr[e], ni[e]);
                mrec[j] = (u64)d | ((u64)nn << 32);
                p[j] = (int)(s[j] / (u32)slice);
                lpos[j] = atomicAdd(&cnt[p[j]], 1);
            } else p[j] = -1;
        }
        __syncthreads();
        if (t < NPART) { gb[t] = lcur[t]; lcur[t] += cnt[t]; }
        __syncthreads();
#pragma unroll
        for (int j = 0; j < SITEMS; ++j) {
            if (p[j] >= 0) {
                const int gi = gb[p[j]] + lpos[j];
                ssrc[gi]  = s[j];
                smrec[gi] = mrec[j];
            }
        }
        __syncthreads();
    }
}

// ---------------------------------------------------------------------------
// k_hist8: per (part, grp): LDS histogram of staged src -> priv[grp][node].
// ---------------------------------------------------------------------------
__global__ __launch_bounds__(1024) void k_hist8(
    const u32* __restrict__ ssrc, const int* __restrict__ pbase,
    int* __restrict__ priv, int n_nodes, int slice)
{
    __shared__ int h[SLICE_MAX];
    const int p = blockIdx.x & (NPART - 1);
    const int g = blockIdx.x >> 3;
    const int t = threadIdx.x;

    const int lo = p * slice;
    const int hi = min(lo + slice, n_nodes);
    const int sl = hi - lo;
    if (sl <= 0) return;

    for (int i = t; i < sl; i += 1024) h[i] = 0;
    __syncthreads();

    const int pb = pbase[p], pe = pbase[p + 1];
    const long long len = pe - pb;
    const int beg = pb + (int)(len * g / EGRP);
    const int end = pb + (int)(len * (g + 1) / EGRP);
    for (int e = beg + t; e < end; e += 1024)
        atomicAdd(&h[(int)ssrc[e] - lo], 1);
    __syncthreads();

    int* __restrict__ dst = priv + (size_t)g * n_nodes + lo;
    for (int i = t; i < sl; i += 1024) dst[i] = h[i];
}

// ---------------------------------------------------------------------------
// Scan pass 1.
// ---------------------------------------------------------------------------
__global__ __launch_bounds__(1024) void k_scan1(
    const int* __restrict__ priv, int* __restrict__ pre,
    int* __restrict__ partials, int n, int n_nodes)
{
    __shared__ int wsum[16];
    const int t = threadIdx.x;
    const int lane = t & 63, wid = t >> 6;
    const int base = blockIdx.x * (SCAN_BLOCK * SCAN_ITEMS) + t * SCAN_ITEMS;

    int v[SCAN_ITEMS];
    int local = 0;
#pragma unroll
    for (int j = 0; j < SCAN_ITEMS; ++j) {
        const int idx = base + j;
        int c = 0;
        if (idx < n) {
            for (int g = 0; g < EGRP; ++g) c += priv[(size_t)g * n_nodes + idx];
        }
        v[j] = local;
        local += c;
    }
    int incl = local;
#pragma unroll
    for (int d = 1; d < 64; d <<= 1) {
        int x = __shfl_up(incl, d);
        if (lane >= d) incl += x;
    }
    if (lane == 63) wsum[wid] = incl;
    __syncthreads();
    if (wid == 0) {
        int s = (lane < 16) ? wsum[lane] : 0;
#pragma unroll
        for (int d = 1; d < 16; d <<= 1) {
            int x = __shfl_up(s, d);
            if (lane >= d) s += x;
        }
        if (lane < 16) wsum[lane] = s;
    }
    __syncthreads();
    const int texcl = (incl - local) + (wid ? wsum[wid - 1] : 0);
#pragma unroll
    for (int j = 0; j < SCAN_ITEMS; ++j) {
        const int idx = base + j;
        if (idx < n) pre[idx] = texcl + v[j];
    }
    if (t == SCAN_BLOCK - 1) partials[blockIdx.x] = texcl + local;
}

// Pass 2: final offsets + per-grp sub-offsets IN-PLACE over priv.
__global__ __launch_bounds__(1024) void k_scan2(
    int* __restrict__ pre, const int* __restrict__ partials,
    int* __restrict__ po, int n, int n_nodes, int n_edges)
{
    __shared__ int s_off;
    const int t = threadIdx.x;
    if (t < 64) {
        int val = (t < blockIdx.x) ? partials[t] : 0;
#pragma unroll
        for (int d = 32; d > 0; d >>= 1) val += __shfl_down(val, d);
        if (t == 0) s_off = val;
    }
    __syncthreads();
    const int boff = s_off;
    const int base = blockIdx.x * (SCAN_BLOCK * SCAN_ITEMS) + t * SCAN_ITEMS;
#pragma unroll
    for (int j = 0; j < SCAN_ITEMS; ++j) {
        const int idx = base + j;
        if (idx < n) {
            const int o = boff + pre[idx];
            pre[idx] = o;
            int running = o;
            for (int g = 0; g < EGRP; ++g) {
                const size_t ix = (size_t)g * n_nodes + idx;
                const int c = po[ix];
                po[ix] = running;
                running += c;
            }
        }
    }
    if (blockIdx.x == 0 && t == 0) pre[n] = n_edges;
}

// ---------------------------------------------------------------------------
// k_place3: LDS cursors seeded from off2; partition-local staged reads.
// ---------------------------------------------------------------------------
__global__ __launch_bounds__(1024) void k_place3(
    const u32* __restrict__ ssrc, const u64* __restrict__ smrec,
    const int* __restrict__ pbase, const int* __restrict__ off2,
    u64* __restrict__ meta2, int n_nodes, int slice)
{
    __shared__ int cur[SLICE_MAX];
    const int p = blockIdx.x & (NPART - 1);
    const int g = blockIdx.x >> 3;
    const int t = threadIdx.x;

    const int lo = p * slice;
    const int hi = min(lo + slice, n_nodes);
    const int sl = hi - lo;
    if (sl <= 0) return;

    const int* __restrict__ o2 = off2 + (size_t)g * n_nodes + lo;
    for (int i = t; i < sl; i += 1024) cur[i] = o2[i];
    __syncthreads();

    const int pb = pbase[p], pe = pbase[p + 1];
    const long long len = pe - pb;
    const int beg = pb + (int)(len * g / EGRP);
    const int end = pb + (int)(len * (g + 1) / EGRP);
    for (int e = beg + t; e < end; e += 1024) {
        const int s = (int)ssrc[e];
        const int pos = atomicAdd(&cur[s - lo], 1);
        meta2[pos] = smrec[e];
    }
}

// ---------------------------------------------------------------------------
// k_gemm (MFMA): [128 rows (node-interleaved real/imag) x 64k] @ [64k x 128f].
// ---------------------------------------------------------------------------
__global__ __launch_bounds__(256, 4) void k_gemm(
    const float* __restrict__ x_real, const float* __restrict__ x_imag,
    const unsigned short* __restrict__ Btp, const float* __restrict__ bias,
    u32* __restrict__ x1p, u32* __restrict__ initp, int n_nodes)
{
    __shared__ unsigned short lds[2 * 128 * 64];   // 32 KB
    unsigned short* __restrict__ A  = lds;
    unsigned short* __restrict__ Bt = lds + 128 * 64;

    const int t = threadIdx.x;
    const int base = blockIdx.x * 64;   // node base

#pragma unroll
    for (int c = 0; c < 8; ++c) {
        const int fq  = t + 256 * c;
        const int arr = fq >> 10;
        const int rem = fq & 1023;
        const int ln  = rem >> 4;
        const int c4  = rem & 15;
        const int g   = base + ln;
        const float* __restrict__ s = arr ? x_imag : x_real;
        float4 v = make_float4(0.f, 0.f, 0.f, 0.f);
        if (g < n_nodes) v = *(const float4*)(s + (size_t)g * F + c4 * 4);
        const int row  = 2 * ln + arr;
        const int kg   = c4 >> 1;
        const int half = c4 & 1;
        u32* dst = (u32*)&A[row * 64 + ((kg ^ (row & 7)) << 3) + (half << 2)];
        dst[0] = pack_bf16x2(v.x, v.y);
        dst[1] = pack_bf16x2(v.z, v.w);
    }

#pragma unroll
    for (int i = 0; i < 4; ++i) {
        const int idx = t + 256 * i;
        ((uint4*)Bt)[idx] = ((const uint4*)Btp)[idx];
    }
    __syncthreads();

    const int l   = t & 63;
    const int w   = t >> 6;
    const int l15 = l & 15;
    const int lg  = l >> 4;

    f32x4 acc[2][8];
#pragma unroll
    for (int tr = 0; tr < 2; ++tr)
#pragma unroll
        for (int tc = 0; tc < 8; ++tc)
            acc[tr][tc] = (f32x4){0.f, 0.f, 0.f, 0.f};

#pragma unroll
    for (int ks = 0; ks < 2; ++ks) {
        bf16x8 af[2];
#pragma unroll
        for (int tr = 0; tr < 2; ++tr) {
            const int row = w * 32 + tr * 16 + l15;
            const int kg  = ks * 4 + lg;
            af[tr] = *(const bf16x8*)&A[row * 64 + ((kg ^ (row & 7)) << 3)];
        }
#pragma unroll
        for (int tc = 0; tc < 8; ++tc) {
            const int f2 = tc * 16 + l15;
            const int kg = ks * 4 + lg;
            const bf16x8 bfr = *(const bf16x8*)&Bt[f2 * 64 + ((kg ^ (f2 & 7)) << 3)];
#pragma unroll
            for (int tr = 0; tr < 2; ++tr)
                acc[tr][tc] = __builtin_amdgcn_mfma_f32_16x16x32_bf16(
                    af[tr], bfr, acc[tr][tc], 0, 0, 0);
        }
    }

#pragma unroll
    for (int tc = 0; tc < 8; ++tc) {
        const int f2 = tc * 16 + l15;
        const float bv = (f2 < F) ? bias[f2] : 0.f;
#pragma unroll
        for (int tr = 0; tr < 2; ++tr) {
            const int row0 = w * 32 + tr * 16 + lg * 4;
            const int g0 = base + (row0 >> 1);
            const int g1 = g0 + 1;
            const f32x4 a = acc[tr][tc];
            if (f2 < F) {
                if (g0 < n_nodes) initp[(size_t)g0 * F + f2] = pack_bf16x2(a[0] + bv, a[1] + bv);
                if (g1 < n_nodes) initp[(size_t)g1 * F + f2] = pack_bf16x2(a[2] + bv, a[3] + bv);
            } else {
                const int f = f2 - F;
                if (g0 < n_nodes) x1p[(size_t)g0 * F + f] = pack_bf16x2(a[0], a[1]);
                if (g1 < n_nodes) x1p[(size_t)g1 * F + f] = pack_bf16x2(a[2], a[3]);
            }
        }
    }
}

// ---------------------------------------------------------------------------
// Gather: partitioned; 16-deep gather pipeline; nt loads for one-touch streams.
// ---------------------------------------------------------------------------
#define APPLY2(m, p, aR, aI)                                  \
    do {                                                      \
        const u32 nnv = (u32)((m) >> 32);                     \
        const float cr = unpack_lo(nnv);                      \
        const float ci = unpack_hi(nnv);                      \
        const float xr = unpack_lo(p);                        \
        const float xi = unpack_hi(p);                        \
        aR = fmaf(cr, xr, fmaf(-ci, xi, aR));                 \
        aI = fmaf(cr, xi, fmaf(ci, xr, aI));                  \
    } while (0)

__global__ __launch_bounds__(256) void k_gather(
    const u32* __restrict__ x1p, const u32* __restrict__ initp,
    const int* __restrict__ offsets, const u64* __restrict__ meta2,
    float* __restrict__ out_real, float* __restrict__ out_imag,
    int n_nodes, int slice)
{
    const int part = blockIdx.x & (NPART - 1);
    const int lane = threadIdx.x & 63;
    const int wip = ((blockIdx.x >> 3) << 2) + (threadIdx.x >> 6);
    const int wpp = (gridDim.x >> 3) << 2;

    const int lo = part * slice;
    const int hi = min(lo + slice, n_nodes);
    if (hi <= lo) return;
    const int chunk = (hi - lo + wpp - 1) / wpp;
    const int nbeg = lo + wip * chunk;
    const int nend = min(nbeg + chunk, hi);

    for (int n = nbeg; n < nend; ++n) {
        const int nu = __builtin_amdgcn_readfirstlane(n);
        const int beg = __builtin_amdgcn_readfirstlane(offsets[nu]);
        const int end = __builtin_amdgcn_readfirstlane(offsets[nu + 1]);

        float aR0 = 0.f, aI0 = 0.f, aR1 = 0.f, aI1 = 0.f;
        float aR2 = 0.f, aI2 = 0.f, aR3 = 0.f, aI3 = 0.f;

        int e = beg;
        for (; e + 16 <= end; e += 16) {
            u64 m[16];
            u32 p[16];
#pragma unroll
            for (int j = 0; j < 16; ++j)
                m[j] = __builtin_nontemporal_load(meta2 + e + j);
#pragma unroll
            for (int j = 0; j < 16; ++j)
                p[j] = x1p[(size_t)(u32)m[j] * F + lane];
#pragma unroll
            for (int j = 0; j < 16; ++j) {
                switch (j & 3) {
                    case 0: APPLY2(m[j], p[j], aR0, aI0); break;
                    case 1: APPLY2(m[j], p[j], aR1, aI1); break;
                    case 2: APPLY2(m[j], p[j], aR2, aI2); break;
                    default: APPLY2(m[j], p[j], aR3, aI3); break;
                }
            }
        }
        for (; e + 4 <= end; e += 4) {
            const u64 m0 = __builtin_nontemporal_load(meta2 + e + 0);
            const u64 m1 = __builtin_nontemporal_load(meta2 + e + 1);
            const u64 m2 = __builtin_nontemporal_load(meta2 + e + 2);
            const u64 m3 = __builtin_nontemporal_load(meta2 + e + 3);
            const u32 p0 = x1p[(size_t)(u32)m0 * F + lane];
            const u32 p1 = x1p[(size_t)(u32)m1 * F + lane];
            const u32 p2 = x1p[(size_t)(u32)m2 * F + lane];
            const u32 p3 = x1p[(size_t)(u32)m3 * F + lane];
            APPLY2(m0, p0, aR0, aI0);
            APPLY2(m1, p1, aR1, aI1);
            APPLY2(m2, p2, aR2, aI2);
            APPLY2(m3, p3, aR3, aI3);
        }
        for (; e < end; ++e) {
            const u64 m = __builtin_nontemporal_load(meta2 + e);
            const u32 p = x1p[(size_t)(u32)m * F + lane];
            APPLY2(m, p, aR0, aI0);
        }

        const size_t b = (size_t)nu * F + lane;
        const u32 iw = __builtin_nontemporal_load(initp + b); // aliases out_real[b]
        const float oR = unpack_lo(iw) + ((aR0 + aR1) + (aR2 + aR3));
        const float oI = unpack_hi(iw) + ((aI0 + aI1) + (aI2 + aI3));
        __builtin_nontemporal_store(oR, &out_real[b]);
        __builtin_nontemporal_store(oI, &out_imag[b]);
    }
}

// ---------------------------------------------------------------------------
// Fallback (ws too small or slice too big): f32 init + atomic scatter.
// ---------------------------------------------------------------------------
__global__ __launch_bounds__(256) void k_init_out(
    const float* __restrict__ x_real, const float* __restrict__ x_imag,
    const float* __restrict__ weight, const float* __restrict__ bias,
    float* __restrict__ out_real, float* __restrict__ out_imag, int n_nodes)
{
    const int lane = threadIdx.x & 63;
    const int waveId = (blockIdx.x * blockDim.x + threadIdx.x) >> 6;
    const int nWaves = (gridDim.x * blockDim.x) >> 6;
    const float* __restrict__ W0 = weight;
    float w0c[F];
#pragma unroll
    for (int k = 0; k < F; ++k) w0c[k] = W0[k * F + lane];
    const float bf = bias[lane];
    for (int n = waveId; n < n_nodes; n += nWaves) {
        const int nu = __builtin_amdgcn_readfirstlane(n);
        const float4* __restrict__ xr4 = (const float4*)(x_real + (size_t)nu * F);
        const float4* __restrict__ xi4 = (const float4*)(x_imag + (size_t)nu * F);
        float gR = 0.f, gI = 0.f;
#pragma unroll
        for (int k4 = 0; k4 < F / 4; ++k4) {
            const float4 vr = xr4[k4];
            const float4 vi = xi4[k4];
            const float xr[4] = {vr.x, vr.y, vr.z, vr.w};
            const float xi[4] = {vi.x, vi.y, vi.z, vi.w};
#pragma unroll
            for (int j = 0; j < 4; ++j) {
                const int k = 4 * k4 + j;
                gR = fmaf(xr[j], w0c[k], gR);
                gI = fmaf(xi[j], w0c[k], gI);
            }
        }
        const size_t b = (size_t)nu * F + lane;
        out_real[b] = gR + bf;
        out_imag[b] = gI + bf;
    }
}

__global__ __launch_bounds__(256) void k_x1_only(
    const float* __restrict__ x_real, const float* __restrict__ x_imag,
    const float* __restrict__ weight, u32* __restrict__ x1p, int n_nodes)
{
    const int lane = threadIdx.x & 63;
    const int waveId = (blockIdx.x * blockDim.x + threadIdx.x) >> 6;
    const int nWaves = (gridDim.x * blockDim.x) >> 6;
    const float* __restrict__ W1 = weight + F * F;
    float w1c[F];
#pragma unroll
    for (int k = 0; k < F; ++k) w1c[k] = W1[k * F + lane];
    for (int n = waveId; n < n_nodes; n += nWaves) {
        const int nu = __builtin_amdgcn_readfirstlane(n);
        const float4* __restrict__ xr4 = (const float4*)(x_real + (size_t)nu * F);
        const float4* __restrict__ xi4 = (const float4*)(x_imag + (size_t)nu * F);
        float aR = 0.f, aI = 0.f;
#pragma unroll
        for (int k4 = 0; k4 < F / 4; ++k4) {
            const float4 vr = xr4[k4];
            const float4 vi = xi4[k4];
            const float xr[4] = {vr.x, vr.y, vr.z, vr.w};
            const float xi[4] = {vi.x, vi.y, vi.z, vi.w};
#pragma unroll
            for (int j = 0; j < 4; ++j) {
                const int k = 4 * k4 + j;
                aR = fmaf(xr[j], w1c[k], aR);
                aI = fmaf(xi[j], w1c[k], aI);
            }
        }
        x1p[(size_t)nu * F + lane] = pack_bf16x2(aR, aI);
    }
}

__global__ __launch_bounds__(256) void k_scatter(
    const u32* __restrict__ x1p, const int* __restrict__ edge_index,
    const float* __restrict__ norm_real, const float* __restrict__ norm_imag,
    float* __restrict__ out_real, float* __restrict__ out_imag, int n_edges)
{
    const long long gid = (long long)blockIdx.x * blockDim.x + threadIdx.x;
    const long long total = (long long)n_edges * 16;
    if (gid >= total) return;
    const int e = (int)(gid >> 4);
    const int c = (int)(gid & 15);
    const int s = edge_index[e];
    const int d = edge_index[n_edges + e];
    const float cr = norm_real[e];
    const float ci = norm_imag[e];
    const uint4 p4 = *(const uint4*)(x1p + (size_t)d * F + c * 4);
    const u32 pp[4] = {p4.x, p4.y, p4.z, p4.w};
    float* __restrict__ pr = out_real + (size_t)s * F + c * 4;
    float* __restrict__ pi = out_imag + (size_t)s * F + c * 4;
#pragma unroll
    for (int j = 0; j < 4; ++j) {
        const float xr = unpack_lo(pp[j]);
        const float xi = unpack_hi(pp[j]);
        unsafeAtomicAdd(pr + j, fmaf(cr, xr, -ci * xi));
        unsafeAtomicAdd(pi + j, fmaf(cr, xi, ci * xr));
    }
}

extern "C" void kernel_launch(void* const* d_in, const int* in_sizes, int n_in,
                              void* d_out, int out_size, void* d_ws, size_t ws_size,
                              hipStream_t stream) {
    const float* x_real     = (const float*)d_in[0];
    const float* x_imag     = (const float*)d_in[1];
    const float* weight     = (const float*)d_in[2];
    const float* bias       = (const float*)d_in[3];
    const float* norm_real  = (const float*)d_in[4];
    const float* norm_imag  = (const float*)d_in[5];
    const int*   edge_index = (const int*)d_in[6];

    const int n_nodes = in_sizes[0] / F;
    const int n_edges = in_sizes[4];
    const int slice   = (n_nodes + NPART - 1) / NPART;

    float* out_real = (float*)d_out;
    float* out_imag = out_real + (size_t)n_nodes * F;
    u32*   initp    = (u32*)d_out;   // packed bf16 init, overwritten by gather

    // ws layout:
    //   region A: staged ssrc(E*4)+smrec(E*8) during CSR build, then x1p
    //   [meta2][offsets][priv(=off2)][partials][bcnt][bbase][pbase][Btp]
    char* ws = (char*)d_ws;
    const size_t x1_bytes     = (size_t)n_nodes * F * sizeof(u32);
    const size_t staged_bytes = (size_t)n_edges * 12;
    const size_t A_bytes      = (x1_bytes > staged_bytes ? x1_bytes : staged_bytes + 8);
    const size_t meta_bytes   = (size_t)n_edges * sizeof(u64);
    const size_t off_bytes    = (size_t)(n_nodes + 1) * sizeof(int);
    const size_t priv_bytes   = (size_t)EGRP * n_nodes * sizeof(int);
    const size_t par_bytes    = 64 * sizeof(int);
    const size_t bcnt_bytes   = (size_t)SPLITB * NPART * sizeof(int);
    const size_t bbase_bytes  = (size_t)SPLITB * NPART * sizeof(int);
    const size_t pbase_bytes  = 64 * sizeof(int);
    const size_t btp_bytes    = 128 * 64 * sizeof(unsigned short);   // 16 KB
    const size_t need = A_bytes + meta_bytes + off_bytes + priv_bytes + par_bytes
                      + bcnt_bytes + bbase_bytes + pbase_bytes + btp_bytes;

    u32* x1p      = (u32*)ws;
    u32* ssrc     = (u32*)ws;
    u64* smrec    = (u64*)(ws + (size_t)n_edges * sizeof(u32));
    u64* meta2    = (u64*)(ws + A_bytes);
    int* offsets  = (int*)(ws + A_bytes + meta_bytes);
    int* priv     = (int*)(ws + A_bytes + meta_bytes + off_bytes);
    int* partials = (int*)(ws + A_bytes + meta_bytes + off_bytes + priv_bytes);
    int* bcnt     = partials + 64;
    int* bbase    = bcnt + SPLITB * NPART;
    int* pbase    = bbase + SPLITB * NPART;
    unsigned short* Btp = (unsigned short*)(pbase + 64);

    if (ws_size >= need && slice <= SLICE_MAX) {
        const int schunk = (n_edges + SPLITB - 1) / SPLITB;
        // --- CSR build (+ fused weight prep in block SPLITB of k_coarse) ---
        k_coarse<<<SPLITB + 1, 256, 0, stream>>>(edge_index, bcnt, weight, Btp,
                                                 n_edges, slice, schunk);
        k_base2<<<1, SPLITB, 0, stream>>>(bcnt, bbase, pbase);
        k_split<<<SPLITB, 256, 0, stream>>>(edge_index, norm_real, norm_imag,
                                            bbase, ssrc, smrec, n_edges, slice, schunk);
        k_hist8<<<NPART * EGRP, 1024, 0, stream>>>(ssrc, pbase, priv, n_nodes, slice);
        const int sblocks = (n_nodes + SCAN_BLOCK * SCAN_ITEMS - 1) / (SCAN_BLOCK * SCAN_ITEMS);
        k_scan1<<<sblocks, SCAN_BLOCK, 0, stream>>>(priv, offsets, partials, n_nodes, n_nodes);
        k_scan2<<<sblocks, SCAN_BLOCK, 0, stream>>>(offsets, partials, priv,
                                                    n_nodes, n_nodes, n_edges);
        k_place3<<<NPART * EGRP, 1024, 0, stream>>>(ssrc, smrec, pbase, priv,
                                                    meta2, n_nodes, slice);
        // --- dense init via MFMA (x1p overwrites staging) + gather ---
        const int gblocks = (n_nodes + 63) / 64;
        k_gemm<<<gblocks, 256, 0, stream>>>(
            x_real, x_imag, Btp, bias, x1p, initp, n_nodes);
        k_gather<<<2048, 256, 0, stream>>>(
            x1p, initp, offsets, meta2, out_real, out_imag, n_nodes, slice);
    } else {
        k_init_out<<<2048, 256, 0, stream>>>(
            x_real, x_imag, weight, bias, out_real, out_imag, n_nodes);
        k_x1_only<<<2048, 256, 0, stream>>>(x_real, x_imag, weight, x1p, n_nodes);
        const long long work = (long long)n_edges * 16;
        const int blocks = (int)((work + 255) / 256);
        k_scatter<<<blocks, 256, 0, stream>>>(
            x1p, edge_index, norm_real, norm_imag, out_real, out_imag, n_edges);
    }
}

// Round 19
// 191.805 us; speedup vs baseline: 1.1923x; 1.0860x over previous
//
#include <hip/hip_runtime.h>

#define F 64
typedef unsigned int u32;
typedef unsigned long long u64;
typedef short bf16x8 __attribute__((ext_vector_type(8)));
typedef float f32x4 __attribute__((ext_vector_type(4)));

#define SCAN_BLOCK 1024
#define SCAN_ITEMS 4   // elements per thread -> 4096 per block
#define NPART 8        // node partitions
#define EGRP 16        // edge groups per partition (grid = 128)
#define SLICE_MAX 12544
#define SPLITB 512     // split blocks (chunks)
#define SITEMS 8       // edges per thread per split round

// ---- bf16x2 pack/unpack (RNE) ----------------------------------------------
__device__ __forceinline__ u32 pack_bf16x2(float lo, float hi) {
    u32 a = __float_as_uint(lo);
    u32 b = __float_as_uint(hi);
    a = (a + 0x7fffu + ((a >> 16) & 1u)) >> 16;
    b = (b + 0x7fffu + ((b >> 16) & 1u)) >> 16;
    return a | (b << 16);
}
__device__ __forceinline__ float unpack_lo(u32 p) { return __uint_as_float(p << 16); }
__device__ __forceinline__ float unpack_hi(u32 p) { return __uint_as_float(p & 0xffff0000u); }

// ---------------------------------------------------------------------------
// k_coarse: per-(block, partition) counts (blocks 0..SPLITB-1) + weight prep
// (block SPLITB): W f32 -> Btp[128][64] bf16 kgroup-swizzled.
// ---------------------------------------------------------------------------
__global__ __launch_bounds__(256) void k_coarse(
    const int* __restrict__ src, int* __restrict__ bcnt,
    const float* __restrict__ weight, unsigned short* __restrict__ Btp,
    int n_edges, int slice, int chunk)
{
    const int t = threadIdx.x;
    if (blockIdx.x == SPLITB) {
        for (int i = t; i < 128 * 64; i += 256) {
            const int f2 = i >> 6;
            const int k  = i & 63;
            const float wv = weight[(f2 >= 64 ? F * F : 0) + k * F + (f2 & 63)];
            Btp[f2 * 64 + (((k >> 3) ^ (f2 & 7)) << 3) + (k & 7)] =
                (unsigned short)(pack_bf16x2(wv, 0.f) & 0xffffu);
        }
        return;
    }
    __shared__ int c[NPART];
    if (t < NPART) c[t] = 0;
    __syncthreads();
    const int cbeg = blockIdx.x * chunk;
    const int cend = min(cbeg + chunk, n_edges);
    for (int e = cbeg + t; e < cend; e += 256)
        atomicAdd(&c[(u32)src[e] / (u32)slice], 1);
    __syncthreads();
    if (t < NPART) bcnt[blockIdx.x * NPART + t] = c[t];
}

// ---------------------------------------------------------------------------
// k_base2: one block. Partition-major scan of bcnt -> bbase + pbase[9].
// ---------------------------------------------------------------------------
__global__ __launch_bounds__(SPLITB) void k_base2(
    const int* __restrict__ bcnt, int* __restrict__ bbase, int* __restrict__ pbase)
{
    __shared__ int wsum[SPLITB / 64];
    __shared__ int total[NPART];
    __shared__ int pb[NPART + 1];
    const int t = threadIdx.x;
    const int lane = t & 63, wid = t >> 6;

    for (int p = 0; p < NPART; ++p) {
        const int v = bcnt[t * NPART + p];
        int incl = v;
#pragma unroll
        for (int d = 1; d < 64; d <<= 1) {
            int x = __shfl_up(incl, d);
            if (lane >= d) incl += x;
        }
        if (lane == 63) wsum[wid] = incl;
        __syncthreads();
        if (wid == 0) {
            int s = (lane < SPLITB / 64) ? wsum[lane] : 0;
#pragma unroll
            for (int d = 1; d < SPLITB / 64; d <<= 1) {
                int x = __shfl_up(s, d);
                if (lane >= d) s += x;
            }
            if (lane < SPLITB / 64) wsum[lane] = s;
        }
        __syncthreads();
        const int excl = (incl - v) + (wid ? wsum[wid - 1] : 0);
        bbase[t * NPART + p] = excl;
        if (t == SPLITB - 1) total[p] = excl + v;
        __syncthreads();
    }
    if (t == 0) {
        int run = 0;
        for (int p = 0; p < NPART; ++p) { pb[p] = run; run += total[p]; }
        pb[NPART] = run;
        for (int p = 0; p <= NPART; ++p) pbase[p] = pb[p];
    }
    __syncthreads();
    for (int p = 0; p < NPART; ++p)
        bbase[t * NPART + p] += pb[p];
}

// ---------------------------------------------------------------------------
// k_split: ONE pass, ZERO global atomics. LDS cursors seeded from bbase.
// ---------------------------------------------------------------------------
__global__ __launch_bounds__(256) void k_split(
    const int* __restrict__ ei, const float* __restrict__ nr, const float* __restrict__ ni,
    const int* __restrict__ bbase, u32* __restrict__ ssrc, u64* __restrict__ smrec,
    int n_edges, int slice, int chunk)
{
    __shared__ int cnt[NPART];
    __shared__ int gb[NPART];
    __shared__ int lcur[NPART];
    const int t = threadIdx.x;
    if (t < NPART) lcur[t] = bbase[blockIdx.x * NPART + t];
    const int cbeg = blockIdx.x * chunk;
    const int cend = min(cbeg + chunk, n_edges);

    for (int base = cbeg; base < cend; base += 256 * SITEMS) {
        if (t < NPART) cnt[t] = 0;
        __syncthreads();
        int p[SITEMS], lpos[SITEMS];
        u32 s[SITEMS]; u64 mrec[SITEMS];
#pragma unroll
        for (int j = 0; j < SITEMS; ++j) {
            const int e = base + t + 256 * j;
            if (e < cend) {
                s[j] = (u32)ei[e];
                const u32 d = (u32)ei[n_edges + e];
                const u32 nn = pack_bf16x2(nr[e], ni[e]);
                mrec[j] = (u64)d | ((u64)nn << 32);
                p[j] = (int)(s[j] / (u32)slice);
                lpos[j] = atomicAdd(&cnt[p[j]], 1);
            } else p[j] = -1;
        }
        __syncthreads();
        if (t < NPART) { gb[t] = lcur[t]; lcur[t] += cnt[t]; }
        __syncthreads();
#pragma unroll
        for (int j = 0; j < SITEMS; ++j) {
            if (p[j] >= 0) {
                const int gi = gb[p[j]] + lpos[j];
                ssrc[gi]  = s[j];
                smrec[gi] = mrec[j];
            }
        }
        __syncthreads();
    }
}

// ---------------------------------------------------------------------------
// k_hist8: per (part, grp): LDS histogram of staged src -> priv[grp][node].
// ---------------------------------------------------------------------------
__global__ __launch_bounds__(1024) void k_hist8(
    const u32* __restrict__ ssrc, const int* __restrict__ pbase,
    int* __restrict__ priv, int n_nodes, int slice)
{
    __shared__ int h[SLICE_MAX];
    const int p = blockIdx.x & (NPART - 1);
    const int g = blockIdx.x >> 3;
    const int t = threadIdx.x;

    const int lo = p * slice;
    const int hi = min(lo + slice, n_nodes);
    const int sl = hi - lo;
    if (sl <= 0) return;

    for (int i = t; i < sl; i += 1024) h[i] = 0;
    __syncthreads();

    const int pb = pbase[p], pe = pbase[p + 1];
    const long long len = pe - pb;
    const int beg = pb + (int)(len * g / EGRP);
    const int end = pb + (int)(len * (g + 1) / EGRP);
    for (int e = beg + t; e < end; e += 1024)
        atomicAdd(&h[(int)ssrc[e] - lo], 1);
    __syncthreads();

    int* __restrict__ dst = priv + (size_t)g * n_nodes + lo;
    for (int i = t; i < sl; i += 1024) dst[i] = h[i];
}

// ---------------------------------------------------------------------------
// Scan pass 1.
// ---------------------------------------------------------------------------
__global__ __launch_bounds__(1024) void k_scan1(
    const int* __restrict__ priv, int* __restrict__ pre,
    int* __restrict__ partials, int n, int n_nodes)
{
    __shared__ int wsum[16];
    const int t = threadIdx.x;
    const int lane = t & 63, wid = t >> 6;
    const int base = blockIdx.x * (SCAN_BLOCK * SCAN_ITEMS) + t * SCAN_ITEMS;

    int v[SCAN_ITEMS];
    int local = 0;
#pragma unroll
    for (int j = 0; j < SCAN_ITEMS; ++j) {
        const int idx = base + j;
        int c = 0;
        if (idx < n) {
            for (int g = 0; g < EGRP; ++g) c += priv[(size_t)g * n_nodes + idx];
        }
        v[j] = local;
        local += c;
    }
    int incl = local;
#pragma unroll
    for (int d = 1; d < 64; d <<= 1) {
        int x = __shfl_up(incl, d);
        if (lane >= d) incl += x;
    }
    if (lane == 63) wsum[wid] = incl;
    __syncthreads();
    if (wid == 0) {
        int s = (lane < 16) ? wsum[lane] : 0;
#pragma unroll
        for (int d = 1; d < 16; d <<= 1) {
            int x = __shfl_up(s, d);
            if (lane >= d) s += x;
        }
        if (lane < 16) wsum[lane] = s;
    }
    __syncthreads();
    const int texcl = (incl - local) + (wid ? wsum[wid - 1] : 0);
#pragma unroll
    for (int j = 0; j < SCAN_ITEMS; ++j) {
        const int idx = base + j;
        if (idx < n) pre[idx] = texcl + v[j];
    }
    if (t == SCAN_BLOCK - 1) partials[blockIdx.x] = texcl + local;
}

// Pass 2: final offsets + per-grp sub-offsets IN-PLACE over priv.
__global__ __launch_bounds__(1024) void k_scan2(
    int* __restrict__ pre, const int* __restrict__ partials,
    int* __restrict__ po, int n, int n_nodes, int n_edges)
{
    __shared__ int s_off;
    const int t = threadIdx.x;
    if (t < 64) {
        int val = (t < blockIdx.x) ? partials[t] : 0;
#pragma unroll
        for (int d = 32; d > 0; d >>= 1) val += __shfl_down(val, d);
        if (t == 0) s_off = val;
    }
    __syncthreads();
    const int boff = s_off;
    const int base = blockIdx.x * (SCAN_BLOCK * SCAN_ITEMS) + t * SCAN_ITEMS;
#pragma unroll
    for (int j = 0; j < SCAN_ITEMS; ++j) {
        const int idx = base + j;
        if (idx < n) {
            const int o = boff + pre[idx];
            pre[idx] = o;
            int running = o;
            for (int g = 0; g < EGRP; ++g) {
                const size_t ix = (size_t)g * n_nodes + idx;
                const int c = po[ix];
                po[ix] = running;
                running += c;
            }
        }
    }
    if (blockIdx.x == 0 && t == 0) pre[n] = n_edges;
}

// ---------------------------------------------------------------------------
// k_place3: LDS cursors seeded from off2; partition-local staged reads.
// ---------------------------------------------------------------------------
__global__ __launch_bounds__(1024) void k_place3(
    const u32* __restrict__ ssrc, const u64* __restrict__ smrec,
    const int* __restrict__ pbase, const int* __restrict__ off2,
    u64* __restrict__ meta2, int n_nodes, int slice)
{
    __shared__ int cur[SLICE_MAX];
    const int p = blockIdx.x & (NPART - 1);
    const int g = blockIdx.x >> 3;
    const int t = threadIdx.x;

    const int lo = p * slice;
    const int hi = min(lo + slice, n_nodes);
    const int sl = hi - lo;
    if (sl <= 0) return;

    const int* __restrict__ o2 = off2 + (size_t)g * n_nodes + lo;
    for (int i = t; i < sl; i += 1024) cur[i] = o2[i];
    __syncthreads();

    const int pb = pbase[p], pe = pbase[p + 1];
    const long long len = pe - pb;
    const int beg = pb + (int)(len * g / EGRP);
    const int end = pb + (int)(len * (g + 1) / EGRP);
    for (int e = beg + t; e < end; e += 1024) {
        const int s = (int)ssrc[e];
        const int pos = atomicAdd(&cur[s - lo], 1);
        meta2[pos] = smrec[e];
    }
}

// ---------------------------------------------------------------------------
// k_gemm (MFMA): [128 rows (node-interleaved real/imag) x 64k] @ [64k x 128f].
// ---------------------------------------------------------------------------
__global__ __launch_bounds__(256, 4) void k_gemm(
    const float* __restrict__ x_real, const float* __restrict__ x_imag,
    const unsigned short* __restrict__ Btp, const float* __restrict__ bias,
    u32* __restrict__ x1p, u32* __restrict__ initp, int n_nodes)
{
    __shared__ unsigned short lds[2 * 128 * 64];   // 32 KB
    unsigned short* __restrict__ A  = lds;
    unsigned short* __restrict__ Bt = lds + 128 * 64;

    const int t = threadIdx.x;
    const int base = blockIdx.x * 64;   // node base

#pragma unroll
    for (int c = 0; c < 8; ++c) {
        const int fq  = t + 256 * c;
        const int arr = fq >> 10;
        const int rem = fq & 1023;
        const int ln  = rem >> 4;
        const int c4  = rem & 15;
        const int g   = base + ln;
        const float* __restrict__ s = arr ? x_imag : x_real;
        float4 v = make_float4(0.f, 0.f, 0.f, 0.f);
        if (g < n_nodes) v = *(const float4*)(s + (size_t)g * F + c4 * 4);
        const int row  = 2 * ln + arr;
        const int kg   = c4 >> 1;
        const int half = c4 & 1;
        u32* dst = (u32*)&A[row * 64 + ((kg ^ (row & 7)) << 3) + (half << 2)];
        dst[0] = pack_bf16x2(v.x, v.y);
        dst[1] = pack_bf16x2(v.z, v.w);
    }

#pragma unroll
    for (int i = 0; i < 4; ++i) {
        const int idx = t + 256 * i;
        ((uint4*)Bt)[idx] = ((const uint4*)Btp)[idx];
    }
    __syncthreads();

    const int l   = t & 63;
    const int w   = t >> 6;
    const int l15 = l & 15;
    const int lg  = l >> 4;

    f32x4 acc[2][8];
#pragma unroll
    for (int tr = 0; tr < 2; ++tr)
#pragma unroll
        for (int tc = 0; tc < 8; ++tc)
            acc[tr][tc] = (f32x4){0.f, 0.f, 0.f, 0.f};

#pragma unroll
    for (int ks = 0; ks < 2; ++ks) {
        bf16x8 af[2];
#pragma unroll
        for (int tr = 0; tr < 2; ++tr) {
            const int row = w * 32 + tr * 16 + l15;
            const int kg  = ks * 4 + lg;
            af[tr] = *(const bf16x8*)&A[row * 64 + ((kg ^ (row & 7)) << 3)];
        }
#pragma unroll
        for (int tc = 0; tc < 8; ++tc) {
            const int f2 = tc * 16 + l15;
            const int kg = ks * 4 + lg;
            const bf16x8 bfr = *(const bf16x8*)&Bt[f2 * 64 + ((kg ^ (f2 & 7)) << 3)];
#pragma unroll
            for (int tr = 0; tr < 2; ++tr)
                acc[tr][tc] = __builtin_amdgcn_mfma_f32_16x16x32_bf16(
                    af[tr], bfr, acc[tr][tc], 0, 0, 0);
        }
    }

#pragma unroll
    for (int tc = 0; tc < 8; ++tc) {
        const int f2 = tc * 16 + l15;
        const float bv = (f2 < F) ? bias[f2] : 0.f;
#pragma unroll
        for (int tr = 0; tr < 2; ++tr) {
            const int row0 = w * 32 + tr * 16 + lg * 4;
            const int g0 = base + (row0 >> 1);
            const int g1 = g0 + 1;
            const f32x4 a = acc[tr][tc];
            if (f2 < F) {
                if (g0 < n_nodes) initp[(size_t)g0 * F + f2] = pack_bf16x2(a[0] + bv, a[1] + bv);
                if (g1 < n_nodes) initp[(size_t)g1 * F + f2] = pack_bf16x2(a[2] + bv, a[3] + bv);
            } else {
                const int f = f2 - F;
                if (g0 < n_nodes) x1p[(size_t)g0 * F + f] = pack_bf16x2(a[0], a[1]);
                if (g1 < n_nodes) x1p[(size_t)g1 * F + f] = pack_bf16x2(a[2], a[3]);
            }
        }
    }
}

// ---------------------------------------------------------------------------
// Gather: partitioned; 8-deep gather pipeline (round-17 measured best);
// nt loads for one-touch streams (meta2, initp).
// ---------------------------------------------------------------------------
#define APPLY2(m, p, aR, aI)                                  \
    do {                                                      \
        const u32 nnv = (u32)((m) >> 32);                     \
        const float cr = unpack_lo(nnv);                      \
        const float ci = unpack_hi(nnv);                      \
        const float xr = unpack_lo(p);                        \
        const float xi = unpack_hi(p);                        \
        aR = fmaf(cr, xr, fmaf(-ci, xi, aR));                 \
        aI = fmaf(cr, xi, fmaf(ci, xr, aI));                  \
    } while (0)

__global__ __launch_bounds__(256) void k_gather(
    const u32* __restrict__ x1p, const u32* __restrict__ initp,
    const int* __restrict__ offsets, const u64* __restrict__ meta2,
    float* __restrict__ out_real, float* __restrict__ out_imag,
    int n_nodes, int slice)
{
    const int part = blockIdx.x & (NPART - 1);
    const int lane = threadIdx.x & 63;
    const int wip = ((blockIdx.x >> 3) << 2) + (threadIdx.x >> 6);
    const int wpp = (gridDim.x >> 3) << 2;

    const int lo = part * slice;
    const int hi = min(lo + slice, n_nodes);
    if (hi <= lo) return;
    const int chunk = (hi - lo + wpp - 1) / wpp;
    const int nbeg = lo + wip * chunk;
    const int nend = min(nbeg + chunk, hi);

    for (int n = nbeg; n < nend; ++n) {
        const int nu = __builtin_amdgcn_readfirstlane(n);
        const int beg = __builtin_amdgcn_readfirstlane(offsets[nu]);
        const int end = __builtin_amdgcn_readfirstlane(offsets[nu + 1]);

        float aR0 = 0.f, aI0 = 0.f, aR1 = 0.f, aI1 = 0.f;
        float aR2 = 0.f, aI2 = 0.f, aR3 = 0.f, aI3 = 0.f;

        int e = beg;
        for (; e + 8 <= end; e += 8) {
            const u64 m0 = __builtin_nontemporal_load(meta2 + e + 0);
            const u64 m1 = __builtin_nontemporal_load(meta2 + e + 1);
            const u64 m2 = __builtin_nontemporal_load(meta2 + e + 2);
            const u64 m3 = __builtin_nontemporal_load(meta2 + e + 3);
            const u64 m4 = __builtin_nontemporal_load(meta2 + e + 4);
            const u64 m5 = __builtin_nontemporal_load(meta2 + e + 5);
            const u64 m6 = __builtin_nontemporal_load(meta2 + e + 6);
            const u64 m7 = __builtin_nontemporal_load(meta2 + e + 7);
            const u32 p0 = x1p[(size_t)(u32)m0 * F + lane];
            const u32 p1 = x1p[(size_t)(u32)m1 * F + lane];
            const u32 p2 = x1p[(size_t)(u32)m2 * F + lane];
            const u32 p3 = x1p[(size_t)(u32)m3 * F + lane];
            const u32 p4 = x1p[(size_t)(u32)m4 * F + lane];
            const u32 p5 = x1p[(size_t)(u32)m5 * F + lane];
            const u32 p6 = x1p[(size_t)(u32)m6 * F + lane];
            const u32 p7 = x1p[(size_t)(u32)m7 * F + lane];
            APPLY2(m0, p0, aR0, aI0);
            APPLY2(m1, p1, aR1, aI1);
            APPLY2(m2, p2, aR2, aI2);
            APPLY2(m3, p3, aR3, aI3);
            APPLY2(m4, p4, aR0, aI0);
            APPLY2(m5, p5, aR1, aI1);
            APPLY2(m6, p6, aR2, aI2);
            APPLY2(m7, p7, aR3, aI3);
        }
        for (; e + 4 <= end; e += 4) {
            const u64 m0 = __builtin_nontemporal_load(meta2 + e + 0);
            const u64 m1 = __builtin_nontemporal_load(meta2 + e + 1);
            const u64 m2 = __builtin_nontemporal_load(meta2 + e + 2);
            const u64 m3 = __builtin_nontemporal_load(meta2 + e + 3);
            const u32 p0 = x1p[(size_t)(u32)m0 * F + lane];
            const u32 p1 = x1p[(size_t)(u32)m1 * F + lane];
            const u32 p2 = x1p[(size_t)(u32)m2 * F + lane];
            const u32 p3 = x1p[(size_t)(u32)m3 * F + lane];
            APPLY2(m0, p0, aR0, aI0);
            APPLY2(m1, p1, aR1, aI1);
            APPLY2(m2, p2, aR2, aI2);
            APPLY2(m3, p3, aR3, aI3);
        }
        for (; e < end; ++e) {
            const u64 m = __builtin_nontemporal_load(meta2 + e);
            const u32 p = x1p[(size_t)(u32)m * F + lane];
            APPLY2(m, p, aR0, aI0);
        }

        const size_t b = (size_t)nu * F + lane;
        const u32 iw = __builtin_nontemporal_load(initp + b); // aliases out_real[b]
        const float oR = unpack_lo(iw) + ((aR0 + aR1) + (aR2 + aR3));
        const float oI = unpack_hi(iw) + ((aI0 + aI1) + (aI2 + aI3));
        __builtin_nontemporal_store(oR, &out_real[b]);
        __builtin_nontemporal_store(oI, &out_imag[b]);
    }
}

// ---------------------------------------------------------------------------
// Fallback (ws too small or slice too big): f32 init + atomic scatter.
// ---------------------------------------------------------------------------
__global__ __launch_bounds__(256) void k_init_out(
    const float* __restrict__ x_real, const float* __restrict__ x_imag,
    const float* __restrict__ weight, const float* __restrict__ bias,
    float* __restrict__ out_real, float* __restrict__ out_imag, int n_nodes)
{
    const int lane = threadIdx.x & 63;
    const int waveId = (blockIdx.x * blockDim.x + threadIdx.x) >> 6;
    const int nWaves = (gridDim.x * blockDim.x) >> 6;
    const float* __restrict__ W0 = weight;
    float w0c[F];
#pragma unroll
    for (int k = 0; k < F; ++k) w0c[k] = W0[k * F + lane];
    const float bf = bias[lane];
    for (int n = waveId; n < n_nodes; n += nWaves) {
        const int nu = __builtin_amdgcn_readfirstlane(n);
        const float4* __restrict__ xr4 = (const float4*)(x_real + (size_t)nu * F);
        const float4* __restrict__ xi4 = (const float4*)(x_imag + (size_t)nu * F);
        float gR = 0.f, gI = 0.f;
#pragma unroll
        for (int k4 = 0; k4 < F / 4; ++k4) {
            const float4 vr = xr4[k4];
            const float4 vi = xi4[k4];
            const float xr[4] = {vr.x, vr.y, vr.z, vr.w};
            const float xi[4] = {vi.x, vi.y, vi.z, vi.w};
#pragma unroll
            for (int j = 0; j < 4; ++j) {
                const int k = 4 * k4 + j;
                gR = fmaf(xr[j], w0c[k], gR);
                gI = fmaf(xi[j], w0c[k], gI);
            }
        }
        const size_t b = (size_t)nu * F + lane;
        out_real[b] = gR + bf;
        out_imag[b] = gI + bf;
    }
}

__global__ __launch_bounds__(256) void k_x1_only(
    const float* __restrict__ x_real, const float* __restrict__ x_imag,
    const float* __restrict__ weight, u32* __restrict__ x1p, int n_nodes)
{
    const int lane = threadIdx.x & 63;
    const int waveId = (blockIdx.x * blockDim.x + threadIdx.x) >> 6;
    const int nWaves = (gridDim.x * blockDim.x) >> 6;
    const float* __restrict__ W1 = weight + F * F;
    float w1c[F];
#pragma unroll
    for (int k = 0; k < F; ++k) w1c[k] = W1[k * F + lane];
    for (int n = waveId; n < n_nodes; n += nWaves) {
        const int nu = __builtin_amdgcn_readfirstlane(n);
        const float4* __restrict__ xr4 = (const float4*)(x_real + (size_t)nu * F);
        const float4* __restrict__ xi4 = (const float4*)(x_imag + (size_t)nu * F);
        float aR = 0.f, aI = 0.f;
#pragma unroll
        for (int k4 = 0; k4 < F / 4; ++k4) {
            const float4 vr = xr4[k4];
            const float4 vi = xi4[k4];
            const float xr[4] = {vr.x, vr.y, vr.z, vr.w};
            const float xi[4] = {vi.x, vi.y, vi.z, vi.w};
#pragma unroll
            for (int j = 0; j < 4; ++j) {
                const int k = 4 * k4 + j;
                aR = fmaf(xr[j], w1c[k], aR);
                aI = fmaf(xi[j], w1c[k], aI);
            }
        }
        x1p[(size_t)nu * F + lane] = pack_bf16x2(aR, aI);
    }
}

__global__ __launch_bounds__(256) void k_scatter(
    const u32* __restrict__ x1p, const int* __restrict__ edge_index,
    const float* __restrict__ norm_real, const float* __restrict__ norm_imag,
    float* __restrict__ out_real, float* __restrict__ out_imag, int n_edges)
{
    const long long gid = (long long)blockIdx.x * blockDim.x + threadIdx.x;
    const long long total = (long long)n_edges * 16;
    if (gid >= total) return;
    const int e = (int)(gid >> 4);
    const int c = (int)(gid & 15);
    const int s = edge_index[e];
    const int d = edge_index[n_edges + e];
    const float cr = norm_real[e];
    const float ci = norm_imag[e];
    const uint4 p4 = *(const uint4*)(x1p + (size_t)d * F + c * 4);
    const u32 pp[4] = {p4.x, p4.y, p4.z, p4.w};
    float* __restrict__ pr = out_real + (size_t)s * F + c * 4;
    float* __restrict__ pi = out_imag + (size_t)s * F + c * 4;
#pragma unroll
    for (int j = 0; j < 4; ++j) {
        const float xr = unpack_lo(pp[j]);
        const float xi = unpack_hi(pp[j]);
        unsafeAtomicAdd(pr + j, fmaf(cr, xr, -ci * xi));
        unsafeAtomicAdd(pi + j, fmaf(cr, xi, ci * xr));
    }
}

extern "C" void kernel_launch(void* const* d_in, const int* in_sizes, int n_in,
                              void* d_out, int out_size, void* d_ws, size_t ws_size,
                              hipStream_t stream) {
    const float* x_real     = (const float*)d_in[0];
    const float* x_imag     = (const float*)d_in[1];
    const float* weight     = (const float*)d_in[2];
    const float* bias       = (const float*)d_in[3];
    const float* norm_real  = (const float*)d_in[4];
    const float* norm_imag  = (const float*)d_in[5];
    const int*   edge_index = (const int*)d_in[6];

    const int n_nodes = in_sizes[0] / F;
    const int n_edges = in_sizes[4];
    const int slice   = (n_nodes + NPART - 1) / NPART;

    float* out_real = (float*)d_out;
    float* out_imag = out_real + (size_t)n_nodes * F;
    u32*   initp    = (u32*)d_out;   // packed bf16 init, overwritten by gather

    // ws layout:
    //   region A: staged ssrc(E*4)+smrec(E*8) during CSR build, then x1p
    //   [meta2][offsets][priv(=off2)][partials][bcnt][bbase][pbase][Btp]
    char* ws = (char*)d_ws;
    const size_t x1_bytes     = (size_t)n_nodes * F * sizeof(u32);
    const size_t staged_bytes = (size_t)n_edges * 12;
    const size_t A_bytes      = (x1_bytes > staged_bytes ? x1_bytes : staged_bytes + 8);
    const size_t meta_bytes   = (size_t)n_edges * sizeof(u64);
    const size_t off_bytes    = (size_t)(n_nodes + 1) * sizeof(int);
    const size_t priv_bytes   = (size_t)EGRP * n_nodes * sizeof(int);
    const size_t par_bytes    = 64 * sizeof(int);
    const size_t bcnt_bytes   = (size_t)SPLITB * NPART * sizeof(int);
    const size_t bbase_bytes  = (size_t)SPLITB * NPART * sizeof(int);
    const size_t pbase_bytes  = 64 * sizeof(int);
    const size_t btp_bytes    = 128 * 64 * sizeof(unsigned short);   // 16 KB
    const size_t need = A_bytes + meta_bytes + off_bytes + priv_bytes + par_bytes
                      + bcnt_bytes + bbase_bytes + pbase_bytes + btp_bytes;

    u32* x1p      = (u32*)ws;
    u32* ssrc     = (u32*)ws;
    u64* smrec    = (u64*)(ws + (size_t)n_edges * sizeof(u32));
    u64* meta2    = (u64*)(ws + A_bytes);
    int* offsets  = (int*)(ws + A_bytes + meta_bytes);
    int* priv     = (int*)(ws + A_bytes + meta_bytes + off_bytes);
    int* partials = (int*)(ws + A_bytes + meta_bytes + off_bytes + priv_bytes);
    int* bcnt     = partials + 64;
    int* bbase    = bcnt + SPLITB * NPART;
    int* pbase    = bbase + SPLITB * NPART;
    unsigned short* Btp = (unsigned short*)(pbase + 64);

    if (ws_size >= need && slice <= SLICE_MAX) {
        const int schunk = (n_edges + SPLITB - 1) / SPLITB;
        // --- CSR build (+ fused weight prep in block SPLITB of k_coarse) ---
        k_coarse<<<SPLITB + 1, 256, 0, stream>>>(edge_index, bcnt, weight, Btp,
                                                 n_edges, slice, schunk);
        k_base2<<<1, SPLITB, 0, stream>>>(bcnt, bbase, pbase);
        k_split<<<SPLITB, 256, 0, stream>>>(edge_index, norm_real, norm_imag,
                                            bbase, ssrc, smrec, n_edges, slice, schunk);
        k_hist8<<<NPART * EGRP, 1024, 0, stream>>>(ssrc, pbase, priv, n_nodes, slice);
        const int sblocks = (n_nodes + SCAN_BLOCK * SCAN_ITEMS - 1) / (SCAN_BLOCK * SCAN_ITEMS);
        k_scan1<<<sblocks, SCAN_BLOCK, 0, stream>>>(priv, offsets, partials, n_nodes, n_nodes);
        k_scan2<<<sblocks, SCAN_BLOCK, 0, stream>>>(offsets, partials, priv,
                                                    n_nodes, n_nodes, n_edges);
        k_place3<<<NPART * EGRP, 1024, 0, stream>>>(ssrc, smrec, pbase, priv,
                                                    meta2, n_nodes, slice);
        // --- dense init via MFMA (x1p overwrites staging) + gather ---
        const int gblocks = (n_nodes + 63) / 64;
        k_gemm<<<gblocks, 256, 0, stream>>>(
            x_real, x_imag, Btp, bias, x1p, initp, n_nodes);
        k_gather<<<2048, 256, 0, stream>>>(
            x1p, initp, offsets, meta2, out_real, out_imag, n_nodes, slice);
    } else {
        k_init_out<<<2048, 256, 0, stream>>>(
            x_real, x_imag, weight, bias, out_real, out_imag, n_nodes);
        k_x1_only<<<2048, 256, 0, stream>>>(x_real, x_imag, weight, x1p, n_nodes);
        const long long work = (long long)n_edges * 16;
        const int blocks = (int)((work + 255) / 256);
        k_scatter<<<blocks, 256, 0, stream>>>(
            x1p, edge_index, norm_real, norm_imag, out_real, out_imag, n_edges);
    }
}

// Round 20
// 187.173 us; speedup vs baseline: 1.2218x; 1.0247x over previous
//
#include <hip/hip_runtime.h>

#define F 64
typedef unsigned int u32;
typedef unsigned long long u64;
typedef short bf16x8 __attribute__((ext_vector_type(8)));
typedef float f32x4 __attribute__((ext_vector_type(4)));

#define SCAN_BLOCK 1024
#define SCAN_ITEMS 4   // elements per thread -> 4096 per block
#define NPART 8        // node partitions
#define EGRP 16        // edge groups per partition (grid = 128)
#define SLICE_MAX 12544
#define SPLITB 512     // split blocks (chunks)
#define SITEMS 8       // edges per thread per split round

// ---- bf16x2 pack/unpack (RNE) ----------------------------------------------
__device__ __forceinline__ u32 pack_bf16x2(float lo, float hi) {
    u32 a = __float_as_uint(lo);
    u32 b = __float_as_uint(hi);
    a = (a + 0x7fffu + ((a >> 16) & 1u)) >> 16;
    b = (b + 0x7fffu + ((b >> 16) & 1u)) >> 16;
    return a | (b << 16);
}
__device__ __forceinline__ float unpack_lo(u32 p) { return __uint_as_float(p << 16); }
__device__ __forceinline__ float unpack_hi(u32 p) { return __uint_as_float(p & 0xffff0000u); }

// ---------------------------------------------------------------------------
// k_coarse: per-(block, partition) counts (blocks 0..SPLITB-1) + weight prep
// (block SPLITB): W f32 -> Btp[128][64] bf16 kgroup-swizzled.
// ---------------------------------------------------------------------------
__global__ __launch_bounds__(256) void k_coarse(
    const int* __restrict__ src, int* __restrict__ bcnt,
    const float* __restrict__ weight, unsigned short* __restrict__ Btp,
    int n_edges, int slice, int chunk)
{
    const int t = threadIdx.x;
    if (blockIdx.x == SPLITB) {
        for (int i = t; i < 128 * 64; i += 256) {
            const int f2 = i >> 6;
            const int k  = i & 63;
            const float wv = weight[(f2 >= 64 ? F * F : 0) + k * F + (f2 & 63)];
            Btp[f2 * 64 + (((k >> 3) ^ (f2 & 7)) << 3) + (k & 7)] =
                (unsigned short)(pack_bf16x2(wv, 0.f) & 0xffffu);
        }
        return;
    }
    __shared__ int c[NPART];
    if (t < NPART) c[t] = 0;
    __syncthreads();
    const int cbeg = blockIdx.x * chunk;
    const int cend = min(cbeg + chunk, n_edges);
    for (int e = cbeg + t; e < cend; e += 256)
        atomicAdd(&c[(u32)src[e] / (u32)slice], 1);
    __syncthreads();
    if (t < NPART) bcnt[blockIdx.x * NPART + t] = c[t];
}

// ---------------------------------------------------------------------------
// k_split: ONE pass, ZERO global atomics. Per-block bases computed inline
// from the bcnt table (16 KB, L2-hot) — no separate base2 kernel.
// ---------------------------------------------------------------------------
__global__ __launch_bounds__(256) void k_split(
    const int* __restrict__ ei, const float* __restrict__ nr, const float* __restrict__ ni,
    const int* __restrict__ bcnt, u32* __restrict__ ssrc, u64* __restrict__ smrec,
    int n_edges, int slice, int chunk)
{
    __shared__ int redAll[NPART][32];
    __shared__ int redPre[NPART][32];
    __shared__ int cnt[NPART];
    __shared__ int gb[NPART];
    __shared__ int lcur[NPART];
    const int t = threadIdx.x;

    // inline bbase: lcur[p] = pbase[p] + sum_{b < bid} bcnt[b][p]
    {
        const int p = t & 7, seg = t >> 3;           // seg in [0,32)
        int sAll = 0, sPre = 0;
        for (int b = seg; b < SPLITB; b += 32) {
            const int v = bcnt[b * NPART + p];
            sAll += v;
            if (b < (int)blockIdx.x) sPre += v;
        }
        redAll[p][seg] = sAll;
        redPre[p][seg] = sPre;
    }
    __syncthreads();
    if (t < NPART) {
        int a = 0, q = 0;
#pragma unroll
        for (int i = 0; i < 32; ++i) { a += redAll[t][i]; q += redPre[t][i]; }
        redAll[t][0] = a;
        redPre[t][0] = q;
    }
    __syncthreads();
    if (t == 0) {
        int run = 0;
        for (int p = 0; p < NPART; ++p) {
            lcur[p] = run + redPre[p][0];
            run += redAll[p][0];
        }
    }
    __syncthreads();

    const int cbeg = blockIdx.x * chunk;
    const int cend = min(cbeg + chunk, n_edges);

    for (int base = cbeg; base < cend; base += 256 * SITEMS) {
        if (t < NPART) cnt[t] = 0;
        __syncthreads();
        int p[SITEMS], lpos[SITEMS];
        u32 s[SITEMS]; u64 mrec[SITEMS];
#pragma unroll
        for (int j = 0; j < SITEMS; ++j) {
            const int e = base + t + 256 * j;
            if (e < cend) {
                s[j] = (u32)ei[e];
                const u32 d = (u32)ei[n_edges + e];
                const u32 nn = pack_bf16x2(nr[e], ni[e]);
                mrec[j] = (u64)d | ((u64)nn << 32);
                p[j] = (int)(s[j] / (u32)slice);
                lpos[j] = atomicAdd(&cnt[p[j]], 1);
            } else p[j] = -1;
        }
        __syncthreads();
        if (t < NPART) { gb[t] = lcur[t]; lcur[t] += cnt[t]; }
        __syncthreads();
#pragma unroll
        for (int j = 0; j < SITEMS; ++j) {
            if (p[j] >= 0) {
                const int gi = gb[p[j]] + lpos[j];
                ssrc[gi]  = s[j];
                smrec[gi] = mrec[j];
            }
        }
        __syncthreads();
    }
}

// ---------------------------------------------------------------------------
// k_hist8: per (part, grp): LDS histogram of staged src -> priv[grp][node].
// pbase computed inline from bcnt.
// ---------------------------------------------------------------------------
__global__ __launch_bounds__(1024) void k_hist8(
    const u32* __restrict__ ssrc, const int* __restrict__ bcnt,
    int* __restrict__ priv, int n_nodes, int slice)
{
    __shared__ int h[SLICE_MAX];
    __shared__ int red[NPART][128];
    __shared__ int pbs[NPART + 1];
    const int p = blockIdx.x & (NPART - 1);
    const int g = blockIdx.x >> 3;
    const int t = threadIdx.x;

    // inline pbase
    {
        const int pp = t & 7, seg = t >> 3;          // seg in [0,128)
        int s = 0;
#pragma unroll 4
        for (int b = seg; b < SPLITB; b += 128) s += bcnt[b * NPART + pp];
        red[pp][seg] = s;
    }
    __syncthreads();
    if (t < NPART) {
        int a = 0;
#pragma unroll
        for (int i = 0; i < 128; ++i) a += red[t][i];
        red[t][0] = a;
    }
    __syncthreads();
    if (t == 0) {
        int run = 0;
        for (int q = 0; q < NPART; ++q) { pbs[q] = run; run += red[q][0]; }
        pbs[NPART] = run;
    }
    __syncthreads();

    const int lo = p * slice;
    const int hi = min(lo + slice, n_nodes);
    const int sl = hi - lo;
    if (sl <= 0) return;

    for (int i = t; i < sl; i += 1024) h[i] = 0;
    __syncthreads();

    const int pb = pbs[p], pe = pbs[p + 1];
    const long long len = pe - pb;
    const int beg = pb + (int)(len * g / EGRP);
    const int end = pb + (int)(len * (g + 1) / EGRP);
    for (int e = beg + t; e < end; e += 1024)
        atomicAdd(&h[(int)ssrc[e] - lo], 1);
    __syncthreads();

    int* __restrict__ dst = priv + (size_t)g * n_nodes + lo;
    for (int i = t; i < sl; i += 1024) dst[i] = h[i];
}

// ---------------------------------------------------------------------------
// Scan pass 1.
// ---------------------------------------------------------------------------
__global__ __launch_bounds__(1024) void k_scan1(
    const int* __restrict__ priv, int* __restrict__ pre,
    int* __restrict__ partials, int n, int n_nodes)
{
    __shared__ int wsum[16];
    const int t = threadIdx.x;
    const int lane = t & 63, wid = t >> 6;
    const int base = blockIdx.x * (SCAN_BLOCK * SCAN_ITEMS) + t * SCAN_ITEMS;

    int v[SCAN_ITEMS];
    int local = 0;
#pragma unroll
    for (int j = 0; j < SCAN_ITEMS; ++j) {
        const int idx = base + j;
        int c = 0;
        if (idx < n) {
            for (int g = 0; g < EGRP; ++g) c += priv[(size_t)g * n_nodes + idx];
        }
        v[j] = local;
        local += c;
    }
    int incl = local;
#pragma unroll
    for (int d = 1; d < 64; d <<= 1) {
        int x = __shfl_up(incl, d);
        if (lane >= d) incl += x;
    }
    if (lane == 63) wsum[wid] = incl;
    __syncthreads();
    if (wid == 0) {
        int s = (lane < 16) ? wsum[lane] : 0;
#pragma unroll
        for (int d = 1; d < 16; d <<= 1) {
            int x = __shfl_up(s, d);
            if (lane >= d) s += x;
        }
        if (lane < 16) wsum[lane] = s;
    }
    __syncthreads();
    const int texcl = (incl - local) + (wid ? wsum[wid - 1] : 0);
#pragma unroll
    for (int j = 0; j < SCAN_ITEMS; ++j) {
        const int idx = base + j;
        if (idx < n) pre[idx] = texcl + v[j];
    }
    if (t == SCAN_BLOCK - 1) partials[blockIdx.x] = texcl + local;
}

// Pass 2: final offsets + per-grp sub-offsets IN-PLACE over priv.
__global__ __launch_bounds__(1024) void k_scan2(
    int* __restrict__ pre, const int* __restrict__ partials,
    int* __restrict__ po, int n, int n_nodes, int n_edges)
{
    __shared__ int s_off;
    const int t = threadIdx.x;
    if (t < 64) {
        int val = (t < blockIdx.x) ? partials[t] : 0;
#pragma unroll
        for (int d = 32; d > 0; d >>= 1) val += __shfl_down(val, d);
        if (t == 0) s_off = val;
    }
    __syncthreads();
    const int boff = s_off;
    const int base = blockIdx.x * (SCAN_BLOCK * SCAN_ITEMS) + t * SCAN_ITEMS;
#pragma unroll
    for (int j = 0; j < SCAN_ITEMS; ++j) {
        const int idx = base + j;
        if (idx < n) {
            const int o = boff + pre[idx];
            pre[idx] = o;
            int running = o;
            for (int g = 0; g < EGRP; ++g) {
                const size_t ix = (size_t)g * n_nodes + idx;
                const int c = po[ix];
                po[ix] = running;
                running += c;
            }
        }
    }
    if (blockIdx.x == 0 && t == 0) pre[n] = n_edges;
}

// ---------------------------------------------------------------------------
// k_place3: LDS cursors seeded from off2; partition-local staged reads.
// pbase computed inline from bcnt.
// ---------------------------------------------------------------------------
__global__ __launch_bounds__(1024) void k_place3(
    const u32* __restrict__ ssrc, const u64* __restrict__ smrec,
    const int* __restrict__ bcnt, const int* __restrict__ off2,
    u64* __restrict__ meta2, int n_nodes, int slice)
{
    __shared__ int cur[SLICE_MAX];
    __shared__ int red[NPART][128];
    __shared__ int pbs[NPART + 1];
    const int p = blockIdx.x & (NPART - 1);
    const int g = blockIdx.x >> 3;
    const int t = threadIdx.x;

    // inline pbase
    {
        const int pp = t & 7, seg = t >> 3;
        int s = 0;
#pragma unroll 4
        for (int b = seg; b < SPLITB; b += 128) s += bcnt[b * NPART + pp];
        red[pp][seg] = s;
    }
    __syncthreads();
    if (t < NPART) {
        int a = 0;
#pragma unroll
        for (int i = 0; i < 128; ++i) a += red[t][i];
        red[t][0] = a;
    }
    __syncthreads();
    if (t == 0) {
        int run = 0;
        for (int q = 0; q < NPART; ++q) { pbs[q] = run; run += red[q][0]; }
        pbs[NPART] = run;
    }
    __syncthreads();

    const int lo = p * slice;
    const int hi = min(lo + slice, n_nodes);
    const int sl = hi - lo;
    if (sl <= 0) return;

    const int* __restrict__ o2 = off2 + (size_t)g * n_nodes + lo;
    for (int i = t; i < sl; i += 1024) cur[i] = o2[i];
    __syncthreads();

    const int pb = pbs[p], pe = pbs[p + 1];
    const long long len = pe - pb;
    const int beg = pb + (int)(len * g / EGRP);
    const int end = pb + (int)(len * (g + 1) / EGRP);
    for (int e = beg + t; e < end; e += 1024) {
        const int s = (int)ssrc[e];
        const int pos = atomicAdd(&cur[s - lo], 1);
        meta2[pos] = smrec[e];
    }
}

// ---------------------------------------------------------------------------
// k_gemm (MFMA): [128 rows (node-interleaved real/imag) x 64k] @ [64k x 128f].
// ---------------------------------------------------------------------------
__global__ __launch_bounds__(256, 4) void k_gemm(
    const float* __restrict__ x_real, const float* __restrict__ x_imag,
    const unsigned short* __restrict__ Btp, const float* __restrict__ bias,
    u32* __restrict__ x1p, u32* __restrict__ initp, int n_nodes)
{
    __shared__ unsigned short lds[2 * 128 * 64];   // 32 KB
    unsigned short* __restrict__ A  = lds;
    unsigned short* __restrict__ Bt = lds + 128 * 64;

    const int t = threadIdx.x;
    const int base = blockIdx.x * 64;   // node base

#pragma unroll
    for (int c = 0; c < 8; ++c) {
        const int fq  = t + 256 * c;
        const int arr = fq >> 10;
        const int rem = fq & 1023;
        const int ln  = rem >> 4;
        const int c4  = rem & 15;
        const int g   = base + ln;
        const float* __restrict__ s = arr ? x_imag : x_real;
        float4 v = make_float4(0.f, 0.f, 0.f, 0.f);
        if (g < n_nodes) v = *(const float4*)(s + (size_t)g * F + c4 * 4);
        const int row  = 2 * ln + arr;
        const int kg   = c4 >> 1;
        const int half = c4 & 1;
        u32* dst = (u32*)&A[row * 64 + ((kg ^ (row & 7)) << 3) + (half << 2)];
        dst[0] = pack_bf16x2(v.x, v.y);
        dst[1] = pack_bf16x2(v.z, v.w);
    }

#pragma unroll
    for (int i = 0; i < 4; ++i) {
        const int idx = t + 256 * i;
        ((uint4*)Bt)[idx] = ((const uint4*)Btp)[idx];
    }
    __syncthreads();

    const int l   = t & 63;
    const int w   = t >> 6;
    const int l15 = l & 15;
    const int lg  = l >> 4;

    f32x4 acc[2][8];
#pragma unroll
    for (int tr = 0; tr < 2; ++tr)
#pragma unroll
        for (int tc = 0; tc < 8; ++tc)
            acc[tr][tc] = (f32x4){0.f, 0.f, 0.f, 0.f};

#pragma unroll
    for (int ks = 0; ks < 2; ++ks) {
        bf16x8 af[2];
#pragma unroll
        for (int tr = 0; tr < 2; ++tr) {
            const int row = w * 32 + tr * 16 + l15;
            const int kg  = ks * 4 + lg;
            af[tr] = *(const bf16x8*)&A[row * 64 + ((kg ^ (row & 7)) << 3)];
        }
#pragma unroll
        for (int tc = 0; tc < 8; ++tc) {
            const int f2 = tc * 16 + l15;
            const int kg = ks * 4 + lg;
            const bf16x8 bfr = *(const bf16x8*)&Bt[f2 * 64 + ((kg ^ (f2 & 7)) << 3)];
#pragma unroll
            for (int tr = 0; tr < 2; ++tr)
                acc[tr][tc] = __builtin_amdgcn_mfma_f32_16x16x32_bf16(
                    af[tr], bfr, acc[tr][tc], 0, 0, 0);
        }
    }

#pragma unroll
    for (int tc = 0; tc < 8; ++tc) {
        const int f2 = tc * 16 + l15;
        const float bv = (f2 < F) ? bias[f2] : 0.f;
#pragma unroll
        for (int tr = 0; tr < 2; ++tr) {
            const int row0 = w * 32 + tr * 16 + lg * 4;
            const int g0 = base + (row0 >> 1);
            const int g1 = g0 + 1;
            const f32x4 a = acc[tr][tc];
            if (f2 < F) {
                if (g0 < n_nodes) initp[(size_t)g0 * F + f2] = pack_bf16x2(a[0] + bv, a[1] + bv);
                if (g1 < n_nodes) initp[(size_t)g1 * F + f2] = pack_bf16x2(a[2] + bv, a[3] + bv);
            } else {
                const int f = f2 - F;
                if (g0 < n_nodes) x1p[(size_t)g0 * F + f] = pack_bf16x2(a[0], a[1]);
                if (g1 < n_nodes) x1p[(size_t)g1 * F + f] = pack_bf16x2(a[2], a[3]);
            }
        }
    }
}

// ---------------------------------------------------------------------------
// Gather: partitioned; 8-deep pipeline; initp load hoisted before edge loop.
// ---------------------------------------------------------------------------
#define APPLY2(m, p, aR, aI)                                  \
    do {                                                      \
        const u32 nnv = (u32)((m) >> 32);                     \
        const float cr = unpack_lo(nnv);                      \
        const float ci = unpack_hi(nnv);                      \
        const float xr = unpack_lo(p);                        \
        const float xi = unpack_hi(p);                        \
        aR = fmaf(cr, xr, fmaf(-ci, xi, aR));                 \
        aI = fmaf(cr, xi, fmaf(ci, xr, aI));                  \
    } while (0)

__global__ __launch_bounds__(256) void k_gather(
    const u32* __restrict__ x1p, const u32* __restrict__ initp,
    const int* __restrict__ offsets, const u64* __restrict__ meta2,
    float* __restrict__ out_real, float* __restrict__ out_imag,
    int n_nodes, int slice)
{
    const int part = blockIdx.x & (NPART - 1);
    const int lane = threadIdx.x & 63;
    const int wip = ((blockIdx.x >> 3) << 2) + (threadIdx.x >> 6);
    const int wpp = (gridDim.x >> 3) << 2;

    const int lo = part * slice;
    const int hi = min(lo + slice, n_nodes);
    if (hi <= lo) return;
    const int chunk = (hi - lo + wpp - 1) / wpp;
    const int nbeg = lo + wip * chunk;
    const int nend = min(nbeg + chunk, hi);

    for (int n = nbeg; n < nend; ++n) {
        const int nu = __builtin_amdgcn_readfirstlane(n);
        const int beg = __builtin_amdgcn_readfirstlane(offsets[nu]);
        const int end = __builtin_amdgcn_readfirstlane(offsets[nu + 1]);

        const size_t b = (size_t)nu * F + lane;
        const u32 iw = __builtin_nontemporal_load(initp + b); // hoisted; aliases out_real[b]

        float aR0 = 0.f, aI0 = 0.f, aR1 = 0.f, aI1 = 0.f;
        float aR2 = 0.f, aI2 = 0.f, aR3 = 0.f, aI3 = 0.f;

        int e = beg;
        for (; e + 8 <= end; e += 8) {
            const u64 m0 = __builtin_nontemporal_load(meta2 + e + 0);
            const u64 m1 = __builtin_nontemporal_load(meta2 + e + 1);
            const u64 m2 = __builtin_nontemporal_load(meta2 + e + 2);
            const u64 m3 = __builtin_nontemporal_load(meta2 + e + 3);
            const u64 m4 = __builtin_nontemporal_load(meta2 + e + 4);
            const u64 m5 = __builtin_nontemporal_load(meta2 + e + 5);
            const u64 m6 = __builtin_nontemporal_load(meta2 + e + 6);
            const u64 m7 = __builtin_nontemporal_load(meta2 + e + 7);
            const u32 p0 = x1p[(size_t)(u32)m0 * F + lane];
            const u32 p1 = x1p[(size_t)(u32)m1 * F + lane];
            const u32 p2 = x1p[(size_t)(u32)m2 * F + lane];
            const u32 p3 = x1p[(size_t)(u32)m3 * F + lane];
            const u32 p4 = x1p[(size_t)(u32)m4 * F + lane];
            const u32 p5 = x1p[(size_t)(u32)m5 * F + lane];
            const u32 p6 = x1p[(size_t)(u32)m6 * F + lane];
            const u32 p7 = x1p[(size_t)(u32)m7 * F + lane];
            APPLY2(m0, p0, aR0, aI0);
            APPLY2(m1, p1, aR1, aI1);
            APPLY2(m2, p2, aR2, aI2);
            APPLY2(m3, p3, aR3, aI3);
            APPLY2(m4, p4, aR0, aI0);
            APPLY2(m5, p5, aR1, aI1);
            APPLY2(m6, p6, aR2, aI2);
            APPLY2(m7, p7, aR3, aI3);
        }
        for (; e + 4 <= end; e += 4) {
            const u64 m0 = __builtin_nontemporal_load(meta2 + e + 0);
            const u64 m1 = __builtin_nontemporal_load(meta2 + e + 1);
            const u64 m2 = __builtin_nontemporal_load(meta2 + e + 2);
            const u64 m3 = __builtin_nontemporal_load(meta2 + e + 3);
            const u32 p0 = x1p[(size_t)(u32)m0 * F + lane];
            const u32 p1 = x1p[(size_t)(u32)m1 * F + lane];
            const u32 p2 = x1p[(size_t)(u32)m2 * F + lane];
            const u32 p3 = x1p[(size_t)(u32)m3 * F + lane];
            APPLY2(m0, p0, aR0, aI0);
            APPLY2(m1, p1, aR1, aI1);
            APPLY2(m2, p2, aR2, aI2);
            APPLY2(m3, p3, aR3, aI3);
        }
        for (; e < end; ++e) {
            const u64 m = __builtin_nontemporal_load(meta2 + e);
            const u32 p = x1p[(size_t)(u32)m * F + lane];
            APPLY2(m, p, aR0, aI0);
        }

        const float oR = unpack_lo(iw) + ((aR0 + aR1) + (aR2 + aR3));
        const float oI = unpack_hi(iw) + ((aI0 + aI1) + (aI2 + aI3));
        __builtin_nontemporal_store(oR, &out_real[b]);
        __builtin_nontemporal_store(oI, &out_imag[b]);
    }
}

// ---------------------------------------------------------------------------
// Fallback (ws too small or slice too big): f32 init + atomic scatter.
// ---------------------------------------------------------------------------
__global__ __launch_bounds__(256) void k_init_out(
    const float* __restrict__ x_real, const float* __restrict__ x_imag,
    const float* __restrict__ weight, const float* __restrict__ bias,
    float* __restrict__ out_real, float* __restrict__ out_imag, int n_nodes)
{
    const int lane = threadIdx.x & 63;
    const int waveId = (blockIdx.x * blockDim.x + threadIdx.x) >> 6;
    const int nWaves = (gridDim.x * blockDim.x) >> 6;
    const float* __restrict__ W0 = weight;
    float w0c[F];
#pragma unroll
    for (int k = 0; k < F; ++k) w0c[k] = W0[k * F + lane];
    const float bf = bias[lane];
    for (int n = waveId; n < n_nodes; n += nWaves) {
        const int nu = __builtin_amdgcn_readfirstlane(n);
        const float4* __restrict__ xr4 = (const float4*)(x_real + (size_t)nu * F);
        const float4* __restrict__ xi4 = (const float4*)(x_imag + (size_t)nu * F);
        float gR = 0.f, gI = 0.f;
#pragma unroll
        for (int k4 = 0; k4 < F / 4; ++k4) {
            const float4 vr = xr4[k4];
            const float4 vi = xi4[k4];
            const float xr[4] = {vr.x, vr.y, vr.z, vr.w};
            const float xi[4] = {vi.x, vi.y, vi.z, vi.w};
#pragma unroll
            for (int j = 0; j < 4; ++j) {
                const int k = 4 * k4 + j;
                gR = fmaf(xr[j], w0c[k], gR);
                gI = fmaf(xi[j], w0c[k], gI);
            }
        }
        const size_t b = (size_t)nu * F + lane;
        out_real[b] = gR + bf;
        out_imag[b] = gI + bf;
    }
}

__global__ __launch_bounds__(256) void k_x1_only(
    const float* __restrict__ x_real, const float* __restrict__ x_imag,
    const float* __restrict__ weight, u32* __restrict__ x1p, int n_nodes)
{
    const int lane = threadIdx.x & 63;
    const int waveId = (blockIdx.x * blockDim.x + threadIdx.x) >> 6;
    const int nWaves = (gridDim.x * blockDim.x) >> 6;
    const float* __restrict__ W1 = weight + F * F;
    float w1c[F];
#pragma unroll
    for (int k = 0; k < F; ++k) w1c[k] = W1[k * F + lane];
    for (int n = waveId; n < n_nodes; n += nWaves) {
        const int nu = __builtin_amdgcn_readfirstlane(n);
        const float4* __restrict__ xr4 = (const float4*)(x_real + (size_t)nu * F);
        const float4* __restrict__ xi4 = (const float4*)(x_imag + (size_t)nu * F);
        float aR = 0.f, aI = 0.f;
#pragma unroll
        for (int k4 = 0; k4 < F / 4; ++k4) {
            const float4 vr = xr4[k4];
            const float4 vi = xi4[k4];
            const float xr[4] = {vr.x, vr.y, vr.z, vr.w};
            const float xi[4] = {vi.x, vi.y, vi.z, vi.w};
#pragma unroll
            for (int j = 0; j < 4; ++j) {
                const int k = 4 * k4 + j;
                aR = fmaf(xr[j], w1c[k], aR);
                aI = fmaf(xi[j], w1c[k], aI);
            }
        }
        x1p[(size_t)nu * F + lane] = pack_bf16x2(aR, aI);
    }
}

__global__ __launch_bounds__(256) void k_scatter(
    const u32* __restrict__ x1p, const int* __restrict__ edge_index,
    const float* __restrict__ norm_real, const float* __restrict__ norm_imag,
    float* __restrict__ out_real, float* __restrict__ out_imag, int n_edges)
{
    const long long gid = (long long)blockIdx.x * blockDim.x + threadIdx.x;
    const long long total = (long long)n_edges * 16;
    if (gid >= total) return;
    const int e = (int)(gid >> 4);
    const int c = (int)(gid & 15);
    const int s = edge_index[e];
    const int d = edge_index[n_edges + e];
    const float cr = norm_real[e];
    const float ci = norm_imag[e];
    const uint4 p4 = *(const uint4*)(x1p + (size_t)d * F + c * 4);
    const u32 pp[4] = {p4.x, p4.y, p4.z, p4.w};
    float* __restrict__ pr = out_real + (size_t)s * F + c * 4;
    float* __restrict__ pi = out_imag + (size_t)s * F + c * 4;
#pragma unroll
    for (int j = 0; j < 4; ++j) {
        const float xr = unpack_lo(pp[j]);
        const float xi = unpack_hi(pp[j]);
        unsafeAtomicAdd(pr + j, fmaf(cr, xr, -ci * xi));
        unsafeAtomicAdd(pi + j, fmaf(cr, xi, ci * xr));
    }
}

extern "C" void kernel_launch(void* const* d_in, const int* in_sizes, int n_in,
                              void* d_out, int out_size, void* d_ws, size_t ws_size,
                              hipStream_t stream) {
    const float* x_real     = (const float*)d_in[0];
    const float* x_imag     = (const float*)d_in[1];
    const float* weight     = (const float*)d_in[2];
    const float* bias       = (const float*)d_in[3];
    const float* norm_real  = (const float*)d_in[4];
    const float* norm_imag  = (const float*)d_in[5];
    const int*   edge_index = (const int*)d_in[6];

    const int n_nodes = in_sizes[0] / F;
    const int n_edges = in_sizes[4];
    const int slice   = (n_nodes + NPART - 1) / NPART;

    float* out_real = (float*)d_out;
    float* out_imag = out_real + (size_t)n_nodes * F;
    u32*   initp    = (u32*)d_out;   // packed bf16 init, overwritten by gather

    // ws layout:
    //   region A: staged ssrc(E*4)+smrec(E*8) during CSR build, then x1p
    //   [meta2][offsets][priv(=off2)][partials][bcnt][Btp]
    char* ws = (char*)d_ws;
    const size_t x1_bytes     = (size_t)n_nodes * F * sizeof(u32);
    const size_t staged_bytes = (size_t)n_edges * 12;
    const size_t A_bytes      = (x1_bytes > staged_bytes ? x1_bytes : staged_bytes + 8);
    const size_t meta_bytes   = (size_t)n_edges * sizeof(u64);
    const size_t off_bytes    = (size_t)(n_nodes + 1) * sizeof(int);
    const size_t priv_bytes   = (size_t)EGRP * n_nodes * sizeof(int);
    const size_t par_bytes    = 64 * sizeof(int);
    const size_t bcnt_bytes   = (size_t)SPLITB * NPART * sizeof(int);
    const size_t btp_bytes    = 128 * 64 * sizeof(unsigned short);   // 16 KB
    const size_t need = A_bytes + meta_bytes + off_bytes + priv_bytes + par_bytes
                      + bcnt_bytes + btp_bytes;

    u32* x1p      = (u32*)ws;
    u32* ssrc     = (u32*)ws;
    u64* smrec    = (u64*)(ws + (size_t)n_edges * sizeof(u32));
    u64* meta2    = (u64*)(ws + A_bytes);
    int* offsets  = (int*)(ws + A_bytes + meta_bytes);
    int* priv     = (int*)(ws + A_bytes + meta_bytes + off_bytes);
    int* partials = (int*)(ws + A_bytes + meta_bytes + off_bytes + priv_bytes);
    int* bcnt     = partials + 64;
    unsigned short* Btp = (unsigned short*)(bcnt + SPLITB * NPART);

    if (ws_size >= need && slice <= SLICE_MAX) {
        const int schunk = (n_edges + SPLITB - 1) / SPLITB;
        // --- CSR build (base prefixes computed inline from bcnt) ---
        k_coarse<<<SPLITB + 1, 256, 0, stream>>>(edge_index, bcnt, weight, Btp,
                                                 n_edges, slice, schunk);
        k_split<<<SPLITB, 256, 0, stream>>>(edge_index, norm_real, norm_imag,
                                            bcnt, ssrc, smrec, n_edges, slice, schunk);
        k_hist8<<<NPART * EGRP, 1024, 0, stream>>>(ssrc, bcnt, priv, n_nodes, slice);
        const int sblocks = (n_nodes + SCAN_BLOCK * SCAN_ITEMS - 1) / (SCAN_BLOCK * SCAN_ITEMS);
        k_scan1<<<sblocks, SCAN_BLOCK, 0, stream>>>(priv, offsets, partials, n_nodes, n_nodes);
        k_scan2<<<sblocks, SCAN_BLOCK, 0, stream>>>(offsets, partials, priv,
                                                    n_nodes, n_nodes, n_edges);
        k_place3<<<NPART * EGRP, 1024, 0, stream>>>(ssrc, smrec, bcnt, priv,
                                                    meta2, n_nodes, slice);
        // --- dense init via MFMA (x1p overwrites staging) + gather ---
        const int gblocks = (n_nodes + 63) / 64;
        k_gemm<<<gblocks, 256, 0, stream>>>(
            x_real, x_imag, Btp, bias, x1p, initp, n_nodes);
        k_gather<<<4096, 256, 0, stream>>>(
            x1p, initp, offsets, meta2, out_real, out_imag, n_nodes, slice);
    } else {
        k_init_out<<<2048, 256, 0, stream>>>(
            x_real, x_imag, weight, bias, out_real, out_imag, n_nodes);
        k_x1_only<<<2048, 256, 0, stream>>>(x_real, x_imag, weight, x1p, n_nodes);
        const long long work = (long long)n_edges * 16;
        const int blocks = (int)((work + 255) / 256);
        k_scatter<<<blocks, 256, 0, stream>>>(
            x1p, edge_index, norm_real, norm_imag, out_real, out_imag, n_edges);
    }
}

// Round 21
// 184.535 us; speedup vs baseline: 1.2393x; 1.0143x over previous
//
#include <hip/hip_runtime.h>

#define F 64
typedef unsigned int u32;
typedef unsigned long long u64;
typedef short bf16x8 __attribute__((ext_vector_type(8)));
typedef float f32x4 __attribute__((ext_vector_type(4)));

#define SCAN_BLOCK 1024
#define SCAN_ITEMS 4   // elements per thread -> 4096 per block
#define NPART 8        // node partitions
#define EGRP 16        // edge groups per partition (grid = 128)
#define SLICE_MAX 12544
#define SPLITB 512     // split blocks (chunks)
#define SITEMS 8       // edges per thread per split round

// srec layout: dst[16:0] | norms[48:17] | srclo[62:49]

// ---- bf16x2 pack/unpack (RNE) ----------------------------------------------
__device__ __forceinline__ u32 pack_bf16x2(float lo, float hi) {
    u32 a = __float_as_uint(lo);
    u32 b = __float_as_uint(hi);
    a = (a + 0x7fffu + ((a >> 16) & 1u)) >> 16;
    b = (b + 0x7fffu + ((b >> 16) & 1u)) >> 16;
    return a | (b << 16);
}
__device__ __forceinline__ float unpack_lo(u32 p) { return __uint_as_float(p << 16); }
__device__ __forceinline__ float unpack_hi(u32 p) { return __uint_as_float(p & 0xffff0000u); }

// ---------------------------------------------------------------------------
// k_coarse: per-(block, partition) counts (blocks 0..SPLITB-1) + weight prep
// (block SPLITB): W f32 -> Btp[128][64] bf16 kgroup-swizzled.
// ---------------------------------------------------------------------------
__global__ __launch_bounds__(256) void k_coarse(
    const int* __restrict__ src, int* __restrict__ bcnt,
    const float* __restrict__ weight, unsigned short* __restrict__ Btp,
    int n_edges, int slice, int chunk)
{
    const int t = threadIdx.x;
    if (blockIdx.x == SPLITB) {
        for (int i = t; i < 128 * 64; i += 256) {
            const int f2 = i >> 6;
            const int k  = i & 63;
            const float wv = weight[(f2 >= 64 ? F * F : 0) + k * F + (f2 & 63)];
            Btp[f2 * 64 + (((k >> 3) ^ (f2 & 7)) << 3) + (k & 7)] =
                (unsigned short)(pack_bf16x2(wv, 0.f) & 0xffffu);
        }
        return;
    }
    __shared__ int c[NPART];
    if (t < NPART) c[t] = 0;
    __syncthreads();
    const int cbeg = blockIdx.x * chunk;
    const int cend = min(cbeg + chunk, n_edges);
    for (int e = cbeg + t; e < cend; e += 256)
        atomicAdd(&c[(u32)src[e] / (u32)slice], 1);
    __syncthreads();
    if (t < NPART) bcnt[blockIdx.x * NPART + t] = c[t];
}

// ---------------------------------------------------------------------------
// k_split: ONE pass, ZERO global atomics. Per-block bases computed inline
// from the bcnt table (16 KB, L2-hot). Writes ONE 8B record/edge.
// ---------------------------------------------------------------------------
__global__ __launch_bounds__(256) void k_split(
    const int* __restrict__ ei, const float* __restrict__ nr, const float* __restrict__ ni,
    const int* __restrict__ bcnt, u64* __restrict__ srec,
    int n_edges, int slice, int chunk)
{
    __shared__ int redAll[NPART][32];
    __shared__ int redPre[NPART][32];
    __shared__ int cnt[NPART];
    __shared__ int gb[NPART];
    __shared__ int lcur[NPART];
    const int t = threadIdx.x;

    // inline bbase: lcur[p] = pbase[p] + sum_{b < bid} bcnt[b][p]
    {
        const int p = t & 7, seg = t >> 3;           // seg in [0,32)
        int sAll = 0, sPre = 0;
        for (int b = seg; b < SPLITB; b += 32) {
            const int v = bcnt[b * NPART + p];
            sAll += v;
            if (b < (int)blockIdx.x) sPre += v;
        }
        redAll[p][seg] = sAll;
        redPre[p][seg] = sPre;
    }
    __syncthreads();
    if (t < NPART) {
        int a = 0, q = 0;
#pragma unroll
        for (int i = 0; i < 32; ++i) { a += redAll[t][i]; q += redPre[t][i]; }
        redAll[t][0] = a;
        redPre[t][0] = q;
    }
    __syncthreads();
    if (t == 0) {
        int run = 0;
        for (int p = 0; p < NPART; ++p) {
            lcur[p] = run + redPre[p][0];
            run += redAll[p][0];
        }
    }
    __syncthreads();

    const int cbeg = blockIdx.x * chunk;
    const int cend = min(cbeg + chunk, n_edges);

    for (int base = cbeg; base < cend; base += 256 * SITEMS) {
        if (t < NPART) cnt[t] = 0;
        __syncthreads();
        int p[SITEMS], lpos[SITEMS];
        u64 mrec[SITEMS];
#pragma unroll
        for (int j = 0; j < SITEMS; ++j) {
            const int e = base + t + 256 * j;
            if (e < cend) {
                const u32 s = (u32)ei[e];
                const u32 d = (u32)ei[n_edges + e];
                const u32 nn = pack_bf16x2(nr[e], ni[e]);
                p[j] = (int)(s / (u32)slice);
                const u32 srclo = s - (u32)p[j] * (u32)slice;
                mrec[j] = (u64)d | ((u64)nn << 17) | ((u64)srclo << 49);
                lpos[j] = atomicAdd(&cnt[p[j]], 1);
            } else p[j] = -1;
        }
        __syncthreads();
        if (t < NPART) { gb[t] = lcur[t]; lcur[t] += cnt[t]; }
        __syncthreads();
#pragma unroll
        for (int j = 0; j < SITEMS; ++j) {
            if (p[j] >= 0) srec[gb[p[j]] + lpos[j]] = mrec[j];
        }
        __syncthreads();
    }
}

// ---------------------------------------------------------------------------
// k_hist8: per (part, grp): LDS histogram of staged srec -> priv[grp][node].
// pbase computed inline from bcnt.
// ---------------------------------------------------------------------------
__global__ __launch_bounds__(1024) void k_hist8(
    const u64* __restrict__ srec, const int* __restrict__ bcnt,
    int* __restrict__ priv, int n_nodes, int slice)
{
    __shared__ int h[SLICE_MAX];
    __shared__ int red[NPART][128];
    __shared__ int pbs[NPART + 1];
    const int p = blockIdx.x & (NPART - 1);
    const int g = blockIdx.x >> 3;
    const int t = threadIdx.x;

    // inline pbase
    {
        const int pp = t & 7, seg = t >> 3;          // seg in [0,128)
        int s = 0;
#pragma unroll 4
        for (int b = seg; b < SPLITB; b += 128) s += bcnt[b * NPART + pp];
        red[pp][seg] = s;
    }
    __syncthreads();
    if (t < NPART) {
        int a = 0;
#pragma unroll
        for (int i = 0; i < 128; ++i) a += red[t][i];
        red[t][0] = a;
    }
    __syncthreads();
    if (t == 0) {
        int run = 0;
        for (int q = 0; q < NPART; ++q) { pbs[q] = run; run += red[q][0]; }
        pbs[NPART] = run;
    }
    __syncthreads();

    const int lo = p * slice;
    const int hi = min(lo + slice, n_nodes);
    const int sl = hi - lo;
    if (sl <= 0) return;

    for (int i = t; i < sl; i += 1024) h[i] = 0;
    __syncthreads();

    const int pb = pbs[p], pe = pbs[p + 1];
    const long long len = pe - pb;
    const int beg = pb + (int)(len * g / EGRP);
    const int end = pb + (int)(len * (g + 1) / EGRP);
    for (int e = beg + t; e < end; e += 1024)
        atomicAdd(&h[(int)(srec[e] >> 49)], 1);
    __syncthreads();

    int* __restrict__ dst = priv + (size_t)g * n_nodes + lo;
    for (int i = t; i < sl; i += 1024) dst[i] = h[i];
}

// ---------------------------------------------------------------------------
// Scan pass 1.
// ---------------------------------------------------------------------------
__global__ __launch_bounds__(1024) void k_scan1(
    const int* __restrict__ priv, int* __restrict__ pre,
    int* __restrict__ partials, int n, int n_nodes)
{
    __shared__ int wsum[16];
    const int t = threadIdx.x;
    const int lane = t & 63, wid = t >> 6;
    const int base = blockIdx.x * (SCAN_BLOCK * SCAN_ITEMS) + t * SCAN_ITEMS;

    int v[SCAN_ITEMS];
    int local = 0;
#pragma unroll
    for (int j = 0; j < SCAN_ITEMS; ++j) {
        const int idx = base + j;
        int c = 0;
        if (idx < n) {
            for (int g = 0; g < EGRP; ++g) c += priv[(size_t)g * n_nodes + idx];
        }
        v[j] = local;
        local += c;
    }
    int incl = local;
#pragma unroll
    for (int d = 1; d < 64; d <<= 1) {
        int x = __shfl_up(incl, d);
        if (lane >= d) incl += x;
    }
    if (lane == 63) wsum[wid] = incl;
    __syncthreads();
    if (wid == 0) {
        int s = (lane < 16) ? wsum[lane] : 0;
#pragma unroll
        for (int d = 1; d < 16; d <<= 1) {
            int x = __shfl_up(s, d);
            if (lane >= d) s += x;
        }
        if (lane < 16) wsum[lane] = s;
    }
    __syncthreads();
    const int texcl = (incl - local) + (wid ? wsum[wid - 1] : 0);
#pragma unroll
    for (int j = 0; j < SCAN_ITEMS; ++j) {
        const int idx = base + j;
        if (idx < n) pre[idx] = texcl + v[j];
    }
    if (t == SCAN_BLOCK - 1) partials[blockIdx.x] = texcl + local;
}

// Pass 2: final offsets + per-grp sub-offsets IN-PLACE over priv.
__global__ __launch_bounds__(1024) void k_scan2(
    int* __restrict__ pre, const int* __restrict__ partials,
    int* __restrict__ po, int n, int n_nodes, int n_edges)
{
    __shared__ int s_off;
    const int t = threadIdx.x;
    if (t < 64) {
        int val = (t < blockIdx.x) ? partials[t] : 0;
#pragma unroll
        for (int d = 32; d > 0; d >>= 1) val += __shfl_down(val, d);
        if (t == 0) s_off = val;
    }
    __syncthreads();
    const int boff = s_off;
    const int base = blockIdx.x * (SCAN_BLOCK * SCAN_ITEMS) + t * SCAN_ITEMS;
#pragma unroll
    for (int j = 0; j < SCAN_ITEMS; ++j) {
        const int idx = base + j;
        if (idx < n) {
            const int o = boff + pre[idx];
            pre[idx] = o;
            int running = o;
            for (int g = 0; g < EGRP; ++g) {
                const size_t ix = (size_t)g * n_nodes + idx;
                const int c = po[ix];
                po[ix] = running;
                running += c;
            }
        }
    }
    if (blockIdx.x == 0 && t == 0) pre[n] = n_edges;
}

// ---------------------------------------------------------------------------
// k_place3: LDS cursors seeded from off2; reads srec only (src embedded).
// ---------------------------------------------------------------------------
__global__ __launch_bounds__(1024) void k_place3(
    const u64* __restrict__ srec, const int* __restrict__ bcnt,
    const int* __restrict__ off2, u64* __restrict__ meta2,
    int n_nodes, int slice)
{
    __shared__ int cur[SLICE_MAX];
    __shared__ int red[NPART][128];
    __shared__ int pbs[NPART + 1];
    const int p = blockIdx.x & (NPART - 1);
    const int g = blockIdx.x >> 3;
    const int t = threadIdx.x;

    // inline pbase
    {
        const int pp = t & 7, seg = t >> 3;
        int s = 0;
#pragma unroll 4
        for (int b = seg; b < SPLITB; b += 128) s += bcnt[b * NPART + pp];
        red[pp][seg] = s;
    }
    __syncthreads();
    if (t < NPART) {
        int a = 0;
#pragma unroll
        for (int i = 0; i < 128; ++i) a += red[t][i];
        red[t][0] = a;
    }
    __syncthreads();
    if (t == 0) {
        int run = 0;
        for (int q = 0; q < NPART; ++q) { pbs[q] = run; run += red[q][0]; }
        pbs[NPART] = run;
    }
    __syncthreads();

    const int lo = p * slice;
    const int hi = min(lo + slice, n_nodes);
    const int sl = hi - lo;
    if (sl <= 0) return;

    const int* __restrict__ o2 = off2 + (size_t)g * n_nodes + lo;
    for (int i = t; i < sl; i += 1024) cur[i] = o2[i];
    __syncthreads();

    const int pb = pbs[p], pe = pbs[p + 1];
    const long long len = pe - pb;
    const int beg = pb + (int)(len * g / EGRP);
    const int end = pb + (int)(len * (g + 1) / EGRP);
    for (int e = beg + t; e < end; e += 1024) {
        const u64 m = srec[e];
        const int pos = atomicAdd(&cur[(int)(m >> 49)], 1);
        meta2[pos] = m;
    }
}

// ---------------------------------------------------------------------------
// k_gemm (MFMA): [128 rows (node-interleaved real/imag) x 64k] @ [64k x 128f].
// ---------------------------------------------------------------------------
__global__ __launch_bounds__(256, 4) void k_gemm(
    const float* __restrict__ x_real, const float* __restrict__ x_imag,
    const unsigned short* __restrict__ Btp, const float* __restrict__ bias,
    u32* __restrict__ x1p, u32* __restrict__ initp, int n_nodes)
{
    __shared__ unsigned short lds[2 * 128 * 64];   // 32 KB
    unsigned short* __restrict__ A  = lds;
    unsigned short* __restrict__ Bt = lds + 128 * 64;

    const int t = threadIdx.x;
    const int base = blockIdx.x * 64;   // node base

#pragma unroll
    for (int c = 0; c < 8; ++c) {
        const int fq  = t + 256 * c;
        const int arr = fq >> 10;
        const int rem = fq & 1023;
        const int ln  = rem >> 4;
        const int c4  = rem & 15;
        const int g   = base + ln;
        const float* __restrict__ s = arr ? x_imag : x_real;
        float4 v = make_float4(0.f, 0.f, 0.f, 0.f);
        if (g < n_nodes) v = *(const float4*)(s + (size_t)g * F + c4 * 4);
        const int row  = 2 * ln + arr;
        const int kg   = c4 >> 1;
        const int half = c4 & 1;
        u32* dst = (u32*)&A[row * 64 + ((kg ^ (row & 7)) << 3) + (half << 2)];
        dst[0] = pack_bf16x2(v.x, v.y);
        dst[1] = pack_bf16x2(v.z, v.w);
    }

#pragma unroll
    for (int i = 0; i < 4; ++i) {
        const int idx = t + 256 * i;
        ((uint4*)Bt)[idx] = ((const uint4*)Btp)[idx];
    }
    __syncthreads();

    const int l   = t & 63;
    const int w   = t >> 6;
    const int l15 = l & 15;
    const int lg  = l >> 4;

    f32x4 acc[2][8];
#pragma unroll
    for (int tr = 0; tr < 2; ++tr)
#pragma unroll
        for (int tc = 0; tc < 8; ++tc)
            acc[tr][tc] = (f32x4){0.f, 0.f, 0.f, 0.f};

#pragma unroll
    for (int ks = 0; ks < 2; ++ks) {
        bf16x8 af[2];
#pragma unroll
        for (int tr = 0; tr < 2; ++tr) {
            const int row = w * 32 + tr * 16 + l15;
            const int kg  = ks * 4 + lg;
            af[tr] = *(const bf16x8*)&A[row * 64 + ((kg ^ (row & 7)) << 3)];
        }
#pragma unroll
        for (int tc = 0; tc < 8; ++tc) {
            const int f2 = tc * 16 + l15;
            const int kg = ks * 4 + lg;
            const bf16x8 bfr = *(const bf16x8*)&Bt[f2 * 64 + ((kg ^ (f2 & 7)) << 3)];
#pragma unroll
            for (int tr = 0; tr < 2; ++tr)
                acc[tr][tc] = __builtin_amdgcn_mfma_f32_16x16x32_bf16(
                    af[tr], bfr, acc[tr][tc], 0, 0, 0);
        }
    }

#pragma unroll
    for (int tc = 0; tc < 8; ++tc) {
        const int f2 = tc * 16 + l15;
        const float bv = (f2 < F) ? bias[f2] : 0.f;
#pragma unroll
        for (int tr = 0; tr < 2; ++tr) {
            const int row0 = w * 32 + tr * 16 + lg * 4;
            const int g0 = base + (row0 >> 1);
            const int g1 = g0 + 1;
            const f32x4 a = acc[tr][tc];
            if (f2 < F) {
                if (g0 < n_nodes) initp[(size_t)g0 * F + f2] = pack_bf16x2(a[0] + bv, a[1] + bv);
                if (g1 < n_nodes) initp[(size_t)g1 * F + f2] = pack_bf16x2(a[2] + bv, a[3] + bv);
            } else {
                const int f = f2 - F;
                if (g0 < n_nodes) x1p[(size_t)g0 * F + f] = pack_bf16x2(a[0], a[1]);
                if (g1 < n_nodes) x1p[(size_t)g1 * F + f] = pack_bf16x2(a[2], a[3]);
            }
        }
    }
}

// ---------------------------------------------------------------------------
// Gather: partitioned; 8-deep pipeline; initp load hoisted; srec-packed meta.
// ---------------------------------------------------------------------------
#define APPLY2(m, p, aR, aI)                                  \
    do {                                                      \
        const u32 nnv = (u32)((m) >> 17);                     \
        const float cr = unpack_lo(nnv);                      \
        const float ci = unpack_hi(nnv);                      \
        const float xr = unpack_lo(p);                        \
        const float xi = unpack_hi(p);                        \
        aR = fmaf(cr, xr, fmaf(-ci, xi, aR));                 \
        aI = fmaf(cr, xi, fmaf(ci, xr, aI));                  \
    } while (0)

#define DSTOF(m) ((size_t)((u32)(m) & 0x1FFFFu))

__global__ __launch_bounds__(256) void k_gather(
    const u32* __restrict__ x1p, const u32* __restrict__ initp,
    const int* __restrict__ offsets, const u64* __restrict__ meta2,
    float* __restrict__ out_real, float* __restrict__ out_imag,
    int n_nodes, int slice)
{
    const int part = blockIdx.x & (NPART - 1);
    const int lane = threadIdx.x & 63;
    const int wip = ((blockIdx.x >> 3) << 2) + (threadIdx.x >> 6);
    const int wpp = (gridDim.x >> 3) << 2;

    const int lo = part * slice;
    const int hi = min(lo + slice, n_nodes);
    if (hi <= lo) return;
    const int chunk = (hi - lo + wpp - 1) / wpp;
    const int nbeg = lo + wip * chunk;
    const int nend = min(nbeg + chunk, hi);

    for (int n = nbeg; n < nend; ++n) {
        const int nu = __builtin_amdgcn_readfirstlane(n);
        const int beg = __builtin_amdgcn_readfirstlane(offsets[nu]);
        const int end = __builtin_amdgcn_readfirstlane(offsets[nu + 1]);

        const size_t b = (size_t)nu * F + lane;
        const u32 iw = __builtin_nontemporal_load(initp + b); // hoisted; aliases out_real[b]

        float aR0 = 0.f, aI0 = 0.f, aR1 = 0.f, aI1 = 0.f;
        float aR2 = 0.f, aI2 = 0.f, aR3 = 0.f, aI3 = 0.f;

        int e = beg;
        for (; e + 8 <= end; e += 8) {
            const u64 m0 = __builtin_nontemporal_load(meta2 + e + 0);
            const u64 m1 = __builtin_nontemporal_load(meta2 + e + 1);
            const u64 m2 = __builtin_nontemporal_load(meta2 + e + 2);
            const u64 m3 = __builtin_nontemporal_load(meta2 + e + 3);
            const u64 m4 = __builtin_nontemporal_load(meta2 + e + 4);
            const u64 m5 = __builtin_nontemporal_load(meta2 + e + 5);
            const u64 m6 = __builtin_nontemporal_load(meta2 + e + 6);
            const u64 m7 = __builtin_nontemporal_load(meta2 + e + 7);
            const u32 p0 = x1p[DSTOF(m0) * F + lane];
            const u32 p1 = x1p[DSTOF(m1) * F + lane];
            const u32 p2 = x1p[DSTOF(m2) * F + lane];
            const u32 p3 = x1p[DSTOF(m3) * F + lane];
            const u32 p4 = x1p[DSTOF(m4) * F + lane];
            const u32 p5 = x1p[DSTOF(m5) * F + lane];
            const u32 p6 = x1p[DSTOF(m6) * F + lane];
            const u32 p7 = x1p[DSTOF(m7) * F + lane];
            APPLY2(m0, p0, aR0, aI0);
            APPLY2(m1, p1, aR1, aI1);
            APPLY2(m2, p2, aR2, aI2);
            APPLY2(m3, p3, aR3, aI3);
            APPLY2(m4, p4, aR0, aI0);
            APPLY2(m5, p5, aR1, aI1);
            APPLY2(m6, p6, aR2, aI2);
            APPLY2(m7, p7, aR3, aI3);
        }
        for (; e + 4 <= end; e += 4) {
            const u64 m0 = __builtin_nontemporal_load(meta2 + e + 0);
            const u64 m1 = __builtin_nontemporal_load(meta2 + e + 1);
            const u64 m2 = __builtin_nontemporal_load(meta2 + e + 2);
            const u64 m3 = __builtin_nontemporal_load(meta2 + e + 3);
            const u32 p0 = x1p[DSTOF(m0) * F + lane];
            const u32 p1 = x1p[DSTOF(m1) * F + lane];
            const u32 p2 = x1p[DSTOF(m2) * F + lane];
            const u32 p3 = x1p[DSTOF(m3) * F + lane];
            APPLY2(m0, p0, aR0, aI0);
            APPLY2(m1, p1, aR1, aI1);
            APPLY2(m2, p2, aR2, aI2);
            APPLY2(m3, p3, aR3, aI3);
        }
        for (; e < end; ++e) {
            const u64 m = __builtin_nontemporal_load(meta2 + e);
            const u32 p = x1p[DSTOF(m) * F + lane];
            APPLY2(m, p, aR0, aI0);
        }

        const float oR = unpack_lo(iw) + ((aR0 + aR1) + (aR2 + aR3));
        const float oI = unpack_hi(iw) + ((aI0 + aI1) + (aI2 + aI3));
        __builtin_nontemporal_store(oR, &out_real[b]);
        __builtin_nontemporal_store(oI, &out_imag[b]);
    }
}

// ---------------------------------------------------------------------------
// Fallback (ws too small, slice too big, or n_nodes > 2^17): f32 init +
// atomic scatter.
// ---------------------------------------------------------------------------
__global__ __launch_bounds__(256) void k_init_out(
    const float* __restrict__ x_real, const float* __restrict__ x_imag,
    const float* __restrict__ weight, const float* __restrict__ bias,
    float* __restrict__ out_real, float* __restrict__ out_imag, int n_nodes)
{
    const int lane = threadIdx.x & 63;
    const int waveId = (blockIdx.x * blockDim.x + threadIdx.x) >> 6;
    const int nWaves = (gridDim.x * blockDim.x) >> 6;
    const float* __restrict__ W0 = weight;
    float w0c[F];
#pragma unroll
    for (int k = 0; k < F; ++k) w0c[k] = W0[k * F + lane];
    const float bf = bias[lane];
    for (int n = waveId; n < n_nodes; n += nWaves) {
        const int nu = __builtin_amdgcn_readfirstlane(n);
        const float4* __restrict__ xr4 = (const float4*)(x_real + (size_t)nu * F);
        const float4* __restrict__ xi4 = (const float4*)(x_imag + (size_t)nu * F);
        float gR = 0.f, gI = 0.f;
#pragma unroll
        for (int k4 = 0; k4 < F / 4; ++k4) {
            const float4 vr = xr4[k4];
            const float4 vi = xi4[k4];
            const float xr[4] = {vr.x, vr.y, vr.z, vr.w};
            const float xi[4] = {vi.x, vi.y, vi.z, vi.w};
#pragma unroll
            for (int j = 0; j < 4; ++j) {
                const int k = 4 * k4 + j;
                gR = fmaf(xr[j], w0c[k], gR);
                gI = fmaf(xi[j], w0c[k], gI);
            }
        }
        const size_t b = (size_t)nu * F + lane;
        out_real[b] = gR + bf;
        out_imag[b] = gI + bf;
    }
}

__global__ __launch_bounds__(256) void k_x1_only(
    const float* __restrict__ x_real, const float* __restrict__ x_imag,
    const float* __restrict__ weight, u32* __restrict__ x1p, int n_nodes)
{
    const int lane = threadIdx.x & 63;
    const int waveId = (blockIdx.x * blockDim.x + threadIdx.x) >> 6;
    const int nWaves = (gridDim.x * blockDim.x) >> 6;
    const float* __restrict__ W1 = weight + F * F;
    float w1c[F];
#pragma unroll
    for (int k = 0; k < F; ++k) w1c[k] = W1[k * F + lane];
    for (int n = waveId; n < n_nodes; n += nWaves) {
        const int nu = __builtin_amdgcn_readfirstlane(n);
        const float4* __restrict__ xr4 = (const float4*)(x_real + (size_t)nu * F);
        const float4* __restrict__ xi4 = (const float4*)(x_imag + (size_t)nu * F);
        float aR = 0.f, aI = 0.f;
#pragma unroll
        for (int k4 = 0; k4 < F / 4; ++k4) {
            const float4 vr = xr4[k4];
            const float4 vi = xi4[k4];
            const float xr[4] = {vr.x, vr.y, vr.z, vr.w};
            const float xi[4] = {vi.x, vi.y, vi.z, vi.w};
#pragma unroll
            for (int j = 0; j < 4; ++j) {
                const int k = 4 * k4 + j;
                aR = fmaf(xr[j], w1c[k], aR);
                aI = fmaf(xi[j], w1c[k], aI);
            }
        }
        x1p[(size_t)nu * F + lane] = pack_bf16x2(aR, aI);
    }
}

__global__ __launch_bounds__(256) void k_scatter(
    const u32* __restrict__ x1p, const int* __restrict__ edge_index,
    const float* __restrict__ norm_real, const float* __restrict__ norm_imag,
    float* __restrict__ out_real, float* __restrict__ out_imag, int n_edges)
{
    const long long gid = (long long)blockIdx.x * blockDim.x + threadIdx.x;
    const long long total = (long long)n_edges * 16;
    if (gid >= total) return;
    const int e = (int)(gid >> 4);
    const int c = (int)(gid & 15);
    const int s = edge_index[e];
    const int d = edge_index[n_edges + e];
    const float cr = norm_real[e];
    const float ci = norm_imag[e];
    const uint4 p4 = *(const uint4*)(x1p + (size_t)d * F + c * 4);
    const u32 pp[4] = {p4.x, p4.y, p4.z, p4.w};
    float* __restrict__ pr = out_real + (size_t)s * F + c * 4;
    float* __restrict__ pi = out_imag + (size_t)s * F + c * 4;
#pragma unroll
    for (int j = 0; j < 4; ++j) {
        const float xr = unpack_lo(pp[j]);
        const float xi = unpack_hi(pp[j]);
        unsafeAtomicAdd(pr + j, fmaf(cr, xr, -ci * xi));
        unsafeAtomicAdd(pi + j, fmaf(cr, xi, ci * xr));
    }
}

extern "C" void kernel_launch(void* const* d_in, const int* in_sizes, int n_in,
                              void* d_out, int out_size, void* d_ws, size_t ws_size,
                              hipStream_t stream) {
    const float* x_real     = (const float*)d_in[0];
    const float* x_imag     = (const float*)d_in[1];
    const float* weight     = (const float*)d_in[2];
    const float* bias       = (const float*)d_in[3];
    const float* norm_real  = (const float*)d_in[4];
    const float* norm_imag  = (const float*)d_in[5];
    const int*   edge_index = (const int*)d_in[6];

    const int n_nodes = in_sizes[0] / F;
    const int n_edges = in_sizes[4];
    const int slice   = (n_nodes + NPART - 1) / NPART;

    float* out_real = (float*)d_out;
    float* out_imag = out_real + (size_t)n_nodes * F;
    u32*   initp    = (u32*)d_out;   // packed bf16 init, overwritten by gather

    // ws layout:
    //   region A: staged srec(E*8) during CSR build, then x1p (sequential reuse)
    //   [meta2][offsets][priv(=off2)][partials][bcnt][Btp]
    char* ws = (char*)d_ws;
    const size_t x1_bytes     = (size_t)n_nodes * F * sizeof(u32);
    const size_t staged_bytes = (size_t)n_edges * sizeof(u64);
    const size_t A_bytes      = (x1_bytes > staged_bytes ? x1_bytes : staged_bytes);
    const size_t meta_bytes   = (size_t)n_edges * sizeof(u64);
    const size_t off_bytes    = (size_t)(n_nodes + 1) * sizeof(int);
    const size_t priv_bytes   = (size_t)EGRP * n_nodes * sizeof(int);
    const size_t par_bytes    = 64 * sizeof(int);
    const size_t bcnt_bytes   = (size_t)SPLITB * NPART * sizeof(int);
    const size_t btp_bytes    = 128 * 64 * sizeof(unsigned short);   // 16 KB
    const size_t need = A_bytes + meta_bytes + off_bytes + priv_bytes + par_bytes
                      + bcnt_bytes + btp_bytes;

    u32* x1p      = (u32*)ws;
    u64* srec     = (u64*)ws;
    u64* meta2    = (u64*)(ws + A_bytes);
    int* offsets  = (int*)(ws + A_bytes + meta_bytes);
    int* priv     = (int*)(ws + A_bytes + meta_bytes + off_bytes);
    int* partials = (int*)(ws + A_bytes + meta_bytes + off_bytes + priv_bytes);
    int* bcnt     = partials + 64;
    unsigned short* Btp = (unsigned short*)(bcnt + SPLITB * NPART);

    if (ws_size >= need && slice <= SLICE_MAX && n_nodes <= (1 << 17)) {
        const int schunk = (n_edges + SPLITB - 1) / SPLITB;
        // --- CSR build (base prefixes computed inline from bcnt) ---
        k_coarse<<<SPLITB + 1, 256, 0, stream>>>(edge_index, bcnt, weight, Btp,
                                                 n_edges, slice, schunk);
        k_split<<<SPLITB, 256, 0, stream>>>(edge_index, norm_real, norm_imag,
                                            bcnt, srec, n_edges, slice, schunk);
        k_hist8<<<NPART * EGRP, 1024, 0, stream>>>(srec, bcnt, priv, n_nodes, slice);
        const int sblocks = (n_nodes + SCAN_BLOCK * SCAN_ITEMS - 1) / (SCAN_BLOCK * SCAN_ITEMS);
        k_scan1<<<sblocks, SCAN_BLOCK, 0, stream>>>(priv, offsets, partials, n_nodes, n_nodes);
        k_scan2<<<sblocks, SCAN_BLOCK, 0, stream>>>(offsets, partials, priv,
                                                    n_nodes, n_nodes, n_edges);
        k_place3<<<NPART * EGRP, 1024, 0, stream>>>(srec, bcnt, priv,
                                                    meta2, n_nodes, slice);
        // --- dense init via MFMA (x1p overwrites staging) + gather ---
        const int gblocks = (n_nodes + 63) / 64;
        k_gemm<<<gblocks, 256, 0, stream>>>(
            x_real, x_imag, Btp, bias, x1p, initp, n_nodes);
        k_gather<<<4096, 256, 0, stream>>>(
            x1p, initp, offsets, meta2, out_real, out_imag, n_nodes, slice);
    } else {
        k_init_out<<<2048, 256, 0, stream>>>(
            x_real, x_imag, weight, bias, out_real, out_imag, n_nodes);
        k_x1_only<<<2048, 256, 0, stream>>>(x_real, x_imag, weight, x1p, n_nodes);
        const long long work = (long long)n_edges * 16;
        const int blocks = (int)((work + 255) / 256);
        k_scatter<<<blocks, 256, 0, stream>>>(
            x1p, edge_index, norm_real, norm_imag, out_real, out_imag, n_edges);
    }
}